// Round 6
// baseline (420.828 us; speedup 1.0000x reference)
//
#include <hip/hip_runtime.h>

#define D_MODEL 1024
#define D_STATE 16
#define M_ROWS  4096   // B*L
#define SEQ_L   1024
#define NSEG    32
#define LSEG    32     // SEQ_L / NSEG

typedef __bf16 bf16x8 __attribute__((ext_vector_type(8)));
typedef float  f32x4  __attribute__((ext_vector_type(4)));

__device__ __forceinline__ unsigned short f2bf(float f) {
  unsigned int u = __builtin_bit_cast(unsigned int, f);
  u += 0x7fffu + ((u >> 16) & 1u);           // RNE
  return (unsigned short)(u >> 16);
}
__device__ __forceinline__ float bf2f(unsigned short b) {
  unsigned int u = ((unsigned int)b) << 16;
  return __builtin_bit_cast(float, u);
}
__device__ __forceinline__ float load_elem(const void* p, size_t i, int isbf) {
  if (isbf) return bf2f(((const unsigned short*)p)[i]);
  return ((const float*)p)[i];
}

// ---------------- dtype detection ----------------
__global__ void detect_kernel(const unsigned short* __restrict__ x, int* __restrict__ flag) {
  __shared__ int cnt;
  if (threadIdx.x == 0) cnt = 0;
  __syncthreads();
  unsigned int v = x[2 * threadIdx.x];
  unsigned int e = (v >> 7) & 0xFFu;
  int ok = (e >= 100u && e <= 135u) ? 1 : 0;
  atomicAdd(&cnt, ok);
  __syncthreads();
  if (threadIdx.x == 0) *flag = (cnt >= 128) ? 1 : 0;
}

// ---------------- x_in -> fp32 (residual/aux) + bf16 (G_big A) ----------------
__global__ void convert_x_kernel(const void* __restrict__ src, float* __restrict__ dstf,
                                 unsigned short* __restrict__ dstb,
                                 const int* __restrict__ flag) {
  int c = blockIdx.x * blockDim.x + threadIdx.x;  // chunk of 8 elems
  int isbf = *flag;
  float o[8];
  if (isbf) {
    uint4 v = ((const uint4*)src)[c];
    o[0] = bf2f((unsigned short)(v.x & 0xffffu)); o[1] = bf2f((unsigned short)(v.x >> 16));
    o[2] = bf2f((unsigned short)(v.y & 0xffffu)); o[3] = bf2f((unsigned short)(v.y >> 16));
    o[4] = bf2f((unsigned short)(v.z & 0xffffu)); o[5] = bf2f((unsigned short)(v.z >> 16));
    o[6] = bf2f((unsigned short)(v.w & 0xffffu)); o[7] = bf2f((unsigned short)(v.w >> 16));
    ((uint4*)dstb)[c] = v;
  } else {
    float4 a = ((const float4*)src)[2 * c];
    float4 b = ((const float4*)src)[2 * c + 1];
    o[0]=a.x; o[1]=a.y; o[2]=a.z; o[3]=a.w; o[4]=b.x; o[5]=b.y; o[6]=b.z; o[7]=b.w;
    uint4 p;
    p.x = (unsigned int)f2bf(o[0]) | ((unsigned int)f2bf(o[1]) << 16);
    p.y = (unsigned int)f2bf(o[2]) | ((unsigned int)f2bf(o[3]) << 16);
    p.z = (unsigned int)f2bf(o[4]) | ((unsigned int)f2bf(o[5]) << 16);
    p.w = (unsigned int)f2bf(o[6]) | ((unsigned int)f2bf(o[7]) << 16);
    ((uint4*)dstb)[c] = p;
  }
  float4* d = (float4*)dstf;
  d[2*c]   = make_float4(o[0], o[1], o[2], o[3]);
  d[2*c+1] = make_float4(o[4], o[5], o[6], o[7]);
}

// ---------------- W_in + W_x -> bf16 (one launch) ----------------
__global__ void convert_w_kernel(const void* __restrict__ w_in, const void* __restrict__ w_x,
                                 unsigned short* __restrict__ d_in, unsigned short* __restrict__ d_x,
                                 const int* __restrict__ flag) {
  int c = blockIdx.x * blockDim.x + threadIdx.x;
  const void* src; unsigned short* dst;
  if (c < 262144) { src = w_in; dst = d_in; }                 // 1024*2048/8
  else { c -= 262144; if (c >= 135168) return; src = w_x; dst = d_x; }  // 1024*1056/8
  int isbf = *flag;
  if (isbf) {
    ((uint4*)dst)[c] = ((const uint4*)src)[c];
  } else {
    float4 a = ((const float4*)src)[2 * c];
    float4 b = ((const float4*)src)[2 * c + 1];
    uint4 p;
    p.x = (unsigned int)f2bf(a.x) | ((unsigned int)f2bf(a.y) << 16);
    p.y = (unsigned int)f2bf(a.z) | ((unsigned int)f2bf(a.w) << 16);
    p.z = (unsigned int)f2bf(b.x) | ((unsigned int)f2bf(b.y) << 16);
    p.w = (unsigned int)f2bf(b.z) | ((unsigned int)f2bf(b.w) << 16);
    ((uint4*)dst)[c] = p;
  }
}

// ---------------- small vectors; A_log -> A2 = -exp(A_log)*log2(e) ----------------
__global__ void convert_smalls_kernel(const void* b_dt, const void* A_log, const void* Dp,
                                      const void* ln_g, const void* ln_b,
                                      float* o_bdt, float* o_a2, float* o_dp,
                                      float* o_lng, float* o_lnb,
                                      const int* __restrict__ flag) {
  int g = blockIdx.x * blockDim.x + threadIdx.x;  // 0..20479
  int isbf = *flag;
  if (g < 1024)              o_bdt[g]          = load_elem(b_dt, g, isbf);
  else if (g < 17408) {
    float v = load_elem(A_log, g - 1024, isbf);
    o_a2[g - 1024] = -expf(v) * 1.4426950408889634f;
  }
  else if (g < 18432)        o_dp[g - 17408]   = load_elem(Dp, g - 17408, isbf);
  else if (g < 19456)        o_lng[g - 18432]  = load_elem(ln_g, g - 18432, isbf);
  else                       o_lnb[g - 19456]  = load_elem(ln_b, g - 19456, isbf);
}

// ---------------- all 4 weight transposes in one launch (grid.z = op) ----------------
__global__ void transpose_all_kernel(const void* __restrict__ s0, const void* __restrict__ s1,
                                     const void* __restrict__ s2, const void* __restrict__ s3,
                                     unsigned short* __restrict__ d0, unsigned short* __restrict__ d1,
                                     unsigned short* __restrict__ d2, unsigned short* __restrict__ d3,
                                     const int* __restrict__ flag) {
  __shared__ float tile[32][33];
  const void* src; unsigned short* dst; int ncols, col0, nx;
  switch (blockIdx.z) {
    case 0:  src = s0; dst = d0; ncols = 2048; col0 = 0;    nx = 64; break;
    case 1:  src = s1; dst = d1; ncols = 1056; col0 = 1024; nx = 4;  break;
    case 2:  src = s2; dst = d2; ncols = 1024; col0 = 0;    nx = 32; break;
    default: src = s3; dst = d3; ncols = 1024; col0 = 0;    nx = 32; break;
  }
  if ((int)blockIdx.x >= nx) return;
  int tx = threadIdx.x, ty = threadIdx.y;   // 32 x 8
  int n0 = col0 + blockIdx.x * 32, k0 = blockIdx.y * 32;
  int isbf = *flag;
  #pragma unroll
  for (int r = 0; r < 4; ++r) {
    int k = k0 + ty + r * 8;
    int n = n0 + tx;
    float v = (n < ncols) ? load_elem(src, (size_t)k * ncols + n, isbf) : 0.f;
    tile[ty + r * 8][tx] = v;
  }
  __syncthreads();
  #pragma unroll
  for (int r = 0; r < 4; ++r) {
    int n = n0 + ty + r * 8;
    int k = k0 + tx;
    dst[(size_t)(n - col0) * 1024 + k] = f2bf(tile[tx][ty + r * 8]);
  }
}

// ---------------- register-direct bf16 MFMA GEMM (no LDS, no barriers) ----------------
// Block = 128 threads = 2 waves; wave w computes the 64x64 tile at
// (m0 = bx*64, n0 = by*128 + w*64). Fragments loaded straight from global as
// 16B vector loads (lane: row = base+lrow+16i, cols quad*8 + 32k), double-
// buffered in registers -> compiler emits s_waitcnt vmcnt(8), 8 loads always
// in flight, MFMA pipe covers L1/L2 latency. Reuse via L1 (waves share A
// panel; consecutive blocks share B panel).
// MODE 0: o0 = bf16 C (ldc 1024)                       [weight precompute]
// MODE 5: bx<16 like MODE0; bx>=16: A=A2, m0=(bx-16)*64, dst=o1  [T2 + BC]
// MODE 1: n<1024 -> x_bf; <2048 -> silu -> s_bf; <3072 -> softplus(v+aux[n-2048]);
//         <3088 -> bssm f32; <3104 -> cssm f32; else discard.
// MODE 4: o0 = f32 (v + aux[m*1024+n])                 [residual]
template<int MODE>
__global__ __launch_bounds__(128, 3) void gemm_rd(
    const unsigned short* __restrict__ A, const unsigned short* __restrict__ A2,
    const unsigned short* __restrict__ Bt, int ldb,
    void* __restrict__ o0, void* __restrict__ o1, void* __restrict__ o2,
    float* __restrict__ o3, float* __restrict__ o4,
    const float* __restrict__ aux) {
  const int wave = threadIdx.x >> 6, lane = threadIdx.x & 63;
  int m0 = blockIdx.x * 64;
  const int n0 = blockIdx.y * 128 + wave * 64;
  const unsigned short* Ap = A;
  if (MODE == 5 && blockIdx.x >= 16) { Ap = A2; m0 = (blockIdx.x - 16) * 64; }
  const int lrow = lane & 15, quad = lane >> 4;

  const unsigned short* pa = Ap + (size_t)(m0 + lrow) * 1024 + quad * 8;
  const unsigned short* pb = Bt + (size_t)(n0 + lrow) * ldb + quad * 8;

  f32x4 acc[4][4];
  #pragma unroll
  for (int i = 0; i < 4; ++i)
    #pragma unroll
    for (int j = 0; j < 4; ++j)
      #pragma unroll
      for (int r = 0; r < 4; ++r) acc[i][j][r] = 0.f;

  bf16x8 af[2][4], bf_[2][4];
  auto load = [&](int buf, int k) {
    #pragma unroll
    for (int i = 0; i < 4; ++i) {
      af[buf][i]  = *(const bf16x8*)(pa + (size_t)i * 16 * 1024 + k * 32);
      bf_[buf][i] = *(const bf16x8*)(pb + (size_t)i * 16 * ldb  + k * 32);
    }
  };
  auto mm = [&](int buf) {
    #pragma unroll
    for (int i = 0; i < 4; ++i)
      #pragma unroll
      for (int j = 0; j < 4; ++j)
        acc[i][j] = __builtin_amdgcn_mfma_f32_16x16x32_bf16(af[buf][i], bf_[buf][j], acc[i][j], 0, 0, 0);
  };

  load(0, 0);
  #pragma unroll
  for (int k = 0; k < 32; ++k) {
    if (k + 1 < 32) load((k + 1) & 1, k + 1);   // prefetch: 8 loads in flight
    mm(k & 1);
  }

  // C/D layout: row = quad*4 + r, col = lane&15.
  #pragma unroll
  for (int i = 0; i < 4; ++i) {
    #pragma unroll
    for (int jj = 0; jj < 4; ++jj) {
      #pragma unroll
      for (int r = 0; r < 4; ++r) {
        int m = m0 + i * 16 + quad * 4 + r;
        int n = n0 + jj * 16 + lrow;
        float v = acc[i][jj][r];
        if (MODE == 0 || MODE == 5) {
          unsigned short* dst = (unsigned short*)o0;
          if (MODE == 5 && blockIdx.x >= 16) dst = (unsigned short*)o1;
          dst[(size_t)m * 1024 + n] = f2bf(v);
        } else if (MODE == 1) {
          if (n < 1024) {
            ((unsigned short*)o0)[(size_t)m * 1024 + n] = f2bf(v);
          } else if (n < 2048) {
            float sig = 1.f / (1.f + expf(-v));
            ((unsigned short*)o1)[(size_t)m * 1024 + (n - 1024)] = f2bf(v * sig);
          } else if (n < 3072) {
            float t = v + aux[n - 2048];
            float sp = (t > 20.f) ? t : log1pf(expf(t));
            ((unsigned short*)o2)[(size_t)m * 1024 + (n - 2048)] = f2bf(sp);
          } else if (n < 3088) {
            o3[(size_t)m * D_STATE + (n - 3072)] = v;
          } else if (n < 3104) {
            o4[(size_t)m * D_STATE + (n - 3088)] = v;
          }
        } else {  // MODE 4
          ((float*)o0)[(size_t)m * 1024 + n] = v + aux[(size_t)m * 1024 + n];
        }
      }
    }
  }
}

// ---------------- chunked parallel scan ----------------
template<int PHASE>
__global__ __launch_bounds__(256) void scan_phase(
    const unsigned short* __restrict__ dl_bf, const unsigned short* __restrict__ x_bf,
    const unsigned short* __restrict__ z_bf, const float* __restrict__ Bs,
    const float* __restrict__ Cs, const float* __restrict__ A2g,
    const float* __restrict__ Dpar, const float* __restrict__ hinit,
    float* __restrict__ Hout, float* __restrict__ sdout,
    unsigned short* __restrict__ g) {
  __shared__ float4 bsh[LSEG][4];
  __shared__ float4 csh[LSEG][4];
  const int tid = threadIdx.x;
  const int bid = blockIdx.x;                 // seg(32) x b(4) x dchunk(4) = 512
  const int seg = bid >> 4;
  const int b = (bid >> 2) & 3;
  const int dc = bid & 3;
  const int d = dc * 256 + tid;
  const int t0 = seg * LSEG;
  const int bd = b * D_MODEL + d;

  if (tid < 128) {                            // stage B (and C) segment rows
    int r = tid >> 2, q = tid & 3;
    size_t src = ((size_t)b * SEQ_L + t0 + r) * 4 + q;
    bsh[r][q] = ((const float4*)Bs)[src];
    if (PHASE == 1) csh[r][q] = ((const float4*)Cs)[src];
  }

  float A2r[16];
  {
    const float4* a4 = (const float4*)(A2g + (size_t)d * 16);
    #pragma unroll
    for (int q = 0; q < 4; ++q) {
      float4 v = a4[q];
      A2r[4*q] = v.x; A2r[4*q+1] = v.y; A2r[4*q+2] = v.z; A2r[4*q+3] = v.w;
    }
  }
  float h[16];
  if (PHASE == 1) {
    const float4* h4 = (const float4*)(hinit + (((size_t)seg * 4096) + bd) * 16);
    #pragma unroll
    for (int q = 0; q < 4; ++q) {
      float4 v = h4[q];
      h[4*q] = v.x; h[4*q+1] = v.y; h[4*q+2] = v.z; h[4*q+3] = v.w;
    }
  } else {
    #pragma unroll
    for (int n = 0; n < 16; ++n) h[n] = 0.f;
  }
  const float Dpd = (PHASE == 1) ? Dpar[d] : 0.f;
  float sd = 0.f;
  const size_t base = ((size_t)b * SEQ_L + t0) * D_MODEL + d;
  __syncthreads();

  unsigned short dreg[2][8], xreg[2][8], zreg[2][8];
  #pragma unroll
  for (int t = 0; t < 8; ++t) {
    size_t o = base + (size_t)t * D_MODEL;
    dreg[0][t] = dl_bf[o]; xreg[0][t] = x_bf[o];
    if (PHASE == 1) zreg[0][t] = z_bf[o];
  }
  #pragma unroll
  for (int c = 0; c < LSEG / 8; ++c) {
    const int cur = c & 1, nxt = cur ^ 1;
    if (c < LSEG / 8 - 1) {                   // prefetch next 8 steps
      #pragma unroll
      for (int t = 0; t < 8; ++t) {
        size_t o = base + (size_t)((c + 1) * 8 + t) * D_MODEL;
        dreg[nxt][t] = dl_bf[o]; xreg[nxt][t] = x_bf[o];
        if (PHASE == 1) zreg[nxt][t] = z_bf[o];
      }
    }
    #pragma unroll
    for (int t = 0; t < 8; ++t) {
      const int tt = c * 8 + t;
      float dl = bf2f(dreg[cur][t]);
      float xx = bf2f(xreg[cur][t]);
      float dx = dl * xx;
      sd += dl;
      float4 b0 = bsh[tt][0], b1 = bsh[tt][1], b2 = bsh[tt][2], b3 = bsh[tt][3];
      float bb[16] = {b0.x,b0.y,b0.z,b0.w, b1.x,b1.y,b1.z,b1.w,
                      b2.x,b2.y,b2.z,b2.w, b3.x,b3.y,b3.z,b3.w};
      if (PHASE == 0) {
        #pragma unroll
        for (int n = 0; n < 16; ++n) {
          float dA = exp2f(dl * A2r[n]);
          h[n] = fmaf(dA, h[n], dx * bb[n]);
        }
      } else {
        float4 c0 = csh[tt][0], c1 = csh[tt][1], c2 = csh[tt][2], c3 = csh[tt][3];
        float cc[16] = {c0.x,c0.y,c0.z,c0.w, c1.x,c1.y,c1.z,c1.w,
                        c2.x,c2.y,c2.z,c2.w, c3.x,c3.y,c3.z,c3.w};
        float y = 0.f;
        #pragma unroll
        for (int n = 0; n < 16; ++n) {
          float dA = exp2f(dl * A2r[n]);
          h[n] = fmaf(dA, h[n], dx * bb[n]);
          y = fmaf(h[n], cc[n], y);
        }
        float zz = bf2f(zreg[cur][t]);
        g[base + (size_t)tt * D_MODEL] = f2bf(fmaf(xx, Dpd, y) * zz);
      }
    }
  }
  if (PHASE == 0) {
    float4* ho = (float4*)(Hout + (((size_t)seg * 4096) + bd) * 16);
    #pragma unroll
    for (int q = 0; q < 4; ++q)
      ho[q] = make_float4(h[4*q], h[4*q+1], h[4*q+2], h[4*q+3]);
    sdout[(size_t)seg * 4096 + bd] = sd;
  }
}

// segment-level scan: h_init(s) = P(s-1)*h_init(s-1) + H(s-1), P = exp2(A2*sumdelta)
__global__ __launch_bounds__(256) void scan_phaseB(
    const float* __restrict__ H, const float* __restrict__ sdelta,
    const float* __restrict__ A2g, float* __restrict__ hinit) {
  int gidx = blockIdx.x * 256 + threadIdx.x;   // 65536 = bd(4096) x n(16)
  int bd = gidx >> 4, n = gidx & 15;
  float A2 = A2g[(size_t)(bd & (D_MODEL - 1)) * 16 + n];
  float hp = 0.f;
  #pragma unroll
  for (int s = 0; s < NSEG; ++s) {
    size_t idx = ((size_t)s * 4096 + bd) * 16 + n;
    hinit[idx] = hp;
    float P = exp2f(A2 * sdelta[(size_t)s * 4096 + bd]);
    hp = fmaf(P, hp, H[idx]);
  }
}

// ---------------- LayerNorm over D=1024 per row ----------------
__global__ __launch_bounds__(256) void ln_kernel(const float* __restrict__ res,
    const float* __restrict__ lng, const float* __restrict__ lnb,
    void* __restrict__ out, const int* __restrict__ flag) {
  int row = blockIdx.x, tid = threadIdx.x;
  const float4* r4 = (const float4*)(res + (size_t)row * D_MODEL);
  float4 v = r4[tid];
  float s = v.x + v.y + v.z + v.w;
  float q = v.x * v.x + v.y * v.y + v.z * v.z + v.w * v.w;
  #pragma unroll
  for (int m = 1; m < 64; m <<= 1) { s += __shfl_xor(s, m); q += __shfl_xor(q, m); }
  __shared__ float ss[4], qs[4];
  int w = tid >> 6;
  if ((tid & 63) == 0) { ss[w] = s; qs[w] = q; }
  __syncthreads();
  s = ss[0] + ss[1] + ss[2] + ss[3];
  q = qs[0] + qs[1] + qs[2] + qs[3];
  float mu = s * (1.f / D_MODEL);
  float var = q * (1.f / D_MODEL) - mu * mu;
  float rstd = rsqrtf(var + 1e-5f);
  float4 gg = ((const float4*)lng)[tid];
  float4 bb = ((const float4*)lnb)[tid];
  float o0 = (v.x - mu) * rstd * gg.x + bb.x;
  float o1 = (v.y - mu) * rstd * gg.y + bb.y;
  float o2 = (v.z - mu) * rstd * gg.z + bb.z;
  float o3 = (v.w - mu) * rstd * gg.w + bb.w;
  if (*flag) {
    ushort4 pv;
    pv.x = f2bf(o0); pv.y = f2bf(o1); pv.z = f2bf(o2); pv.w = f2bf(o3);
    ((ushort4*)out)[(size_t)row * 256 + tid] = pv;
  } else {
    ((float4*)out)[(size_t)row * 256 + tid] = make_float4(o0, o1, o2, o3);
  }
}

extern "C" void kernel_launch(void* const* d_in, const int* in_sizes, int n_in,
                              void* d_out, int out_size, void* d_ws, size_t ws_size,
                              hipStream_t stream) {
  (void)in_sizes; (void)n_in; (void)out_size; (void)ws_size;
  const void* x_in  = d_in[0];
  const void* W_in  = d_in[1];
  const void* W_x   = d_in[2];
  const void* W_dt  = d_in[3];
  const void* b_dt  = d_in[4];
  const void* A_log = d_in[5];
  const void* D_par = d_in[6];
  const void* W_out = d_in[7];
  const void* ln_g  = d_in[8];
  const void* ln_b  = d_in[9];

  char* ws = (char*)d_ws;
  size_t off = 0;
  auto alloc = [&](size_t bytes) -> void* {
    void* p = ws + off;
    off += (bytes + 255) & ~(size_t)255;
    return p;
  };
  int* flag              = (int*)alloc(16);
  float* x_in_f          = (float*)alloc((size_t)M_ROWS * D_MODEL * 4);
  unsigned short* x_in_b = (unsigned short*)alloc((size_t)M_ROWS * D_MODEL * 2);
  float* bdt_f           = (float*)alloc(1024 * 4);
  float* a2_f            = (float*)alloc(16384 * 4);
  float* dp_f            = (float*)alloc(1024 * 4);
  float* lng_f           = (float*)alloc(1024 * 4);
  float* lnb_f           = (float*)alloc(1024 * 4);
  unsigned short* win_raw= (unsigned short*)alloc((size_t)1024 * 2048 * 2);  // W_in bf16, ldb 2048
  unsigned short* wx_raw = (unsigned short*)alloc((size_t)1024 * 1056 * 2);  // W_x bf16, ldb 1056
  unsigned short* wt_dt  = (unsigned short*)alloc((size_t)1024 * 1024 * 2);  // W_dt^T
  unsigned short* wt_out = (unsigned short*)alloc((size_t)1024 * 1024 * 2);  // W_out^T
  unsigned short* wt_xbc = (unsigned short*)alloc((size_t)128 * 1024 * 2);   // Wx cols 1024..1151 ^T
  unsigned short* U_bf   = (unsigned short*)alloc((size_t)1024 * 1024 * 2);  // (Wx_d @ W_dt)^T
  unsigned short* btbig  = (unsigned short*)alloc((size_t)3328 * 1024 * 2);  // [Win^T|Wd^T|Wbc^T|pad]
  unsigned short* x_bf   = (unsigned short*)alloc((size_t)M_ROWS * D_MODEL * 2);
  unsigned short* s_bf   = (unsigned short*)alloc((size_t)M_ROWS * D_MODEL * 2);  // silu(z)
  unsigned short* delta_bf=(unsigned short*)alloc((size_t)M_ROWS * D_MODEL * 2);
  float* bssm_f          = (float*)alloc((size_t)M_ROWS * D_STATE * 4);
  float* cssm_f          = (float*)alloc((size_t)M_ROWS * D_STATE * 4);
  float* H_f             = (float*)alloc((size_t)NSEG * 4096 * 16 * 4);
  float* hinit_f         = (float*)alloc((size_t)NSEG * 4096 * 16 * 4);
  float* sdelta_f        = (float*)alloc((size_t)NSEG * 4096 * 4);
  unsigned short* g_bf   = (unsigned short*)alloc((size_t)M_ROWS * D_MODEL * 2);
  float* res_f = (float*)x_bf;   // alias: x_bf+s_bf (16MB contiguous) consumed by scan1
                                 // before GEMM4 writes res

  detect_kernel<<<1, 256, 0, stream>>>((const unsigned short*)x_in, flag);
  convert_x_kernel<<<2048, 256, 0, stream>>>(x_in, x_in_f, x_in_b, flag);
  convert_smalls_kernel<<<80, 256, 0, stream>>>(b_dt, A_log, D_par, ln_g, ln_b,
                                                bdt_f, a2_f, dp_f, lng_f, lnb_f, flag);
  convert_w_kernel<<<1553, 256, 0, stream>>>(W_in, W_x, win_raw, wx_raw, flag);
  dim3 tb(32, 8);
  transpose_all_kernel<<<dim3(64, 32, 4), tb, 0, stream>>>(
      W_in, W_x, W_dt, W_out, btbig, wt_xbc, wt_dt, wt_out, flag);

  // precompute: U = (Wx_d @ W_dt)^T; then one launch computes
  // T2 = (Win_x Wx_d W_dt)^T (bx<16) and BC = (Win_x Wx_bc)^T (bx>=16).
  gemm_rd<0><<<dim3(16, 8), 128, 0, stream>>>(wt_dt, nullptr, wx_raw, 1056, U_bf,
                                              nullptr, nullptr, nullptr, nullptr, nullptr);
  gemm_rd<5><<<dim3(18, 8), 128, 0, stream>>>(U_bf, wt_xbc, win_raw, 2048,
                                              btbig + (size_t)2048 * 1024,
                                              btbig + (size_t)3072 * 1024,
                                              nullptr, nullptr, nullptr, nullptr);

  // the one big forward GEMM: x_in @ [Win | Wdelta | Wbc]
  gemm_rd<1><<<dim3(64, 25), 128, 0, stream>>>(x_in_b, nullptr, btbig, 1024,
                                               x_bf, s_bf, delta_bf, bssm_f, cssm_f, bdt_f);

  scan_phase<0><<<512, 256, 0, stream>>>(delta_bf, x_bf, nullptr, bssm_f, nullptr,
                                         a2_f, nullptr, nullptr, H_f, sdelta_f, nullptr);
  scan_phaseB<<<256, 256, 0, stream>>>(H_f, sdelta_f, a2_f, hinit_f);
  scan_phase<1><<<512, 256, 0, stream>>>(delta_bf, x_bf, s_bf, bssm_f, cssm_f,
                                         a2_f, dp_f, hinit_f, nullptr, nullptr, g_bf);

  gemm_rd<4><<<dim3(64, 8), 128, 0, stream>>>(g_bf, nullptr, wt_out, 1024,
                                              res_f, nullptr, nullptr, nullptr, nullptr, x_in_f);
  ln_kernel<<<4096, 256, 0, stream>>>(res_f, lng_f, lnb_f, d_out, flag);
}

// Round 7
// 279.590 us; speedup vs baseline: 1.5052x; 1.5052x over previous
//
#include <hip/hip_runtime.h>

#define D_MODEL 1024
#define D_STATE 16
#define M_ROWS  4096   // B*L
#define SEQ_L   1024
#define NSEG    64
#define LSEG    16     // SEQ_L / NSEG

typedef __bf16 bf16x8 __attribute__((ext_vector_type(8)));
typedef float  f32x4  __attribute__((ext_vector_type(4)));

__device__ __forceinline__ unsigned short f2bf(float f) {
  unsigned int u = __builtin_bit_cast(unsigned int, f);
  u += 0x7fffu + ((u >> 16) & 1u);           // RNE
  return (unsigned short)(u >> 16);
}
__device__ __forceinline__ float bf2f(unsigned short b) {
  unsigned int u = ((unsigned int)b) << 16;
  return __builtin_bit_cast(float, u);
}
__device__ __forceinline__ float load_elem(const void* p, size_t i, int isbf) {
  if (isbf) return bf2f(((const unsigned short*)p)[i]);
  return ((const float*)p)[i];
}

// async global->LDS, 16B per lane. LDS dest = (wave-uniform base) + lane*16.
__device__ __forceinline__ void gload16(const void* g, void* l) {
  typedef const __attribute__((address_space(1))) unsigned int GU;
  typedef __attribute__((address_space(3))) unsigned int LU;
  __builtin_amdgcn_global_load_lds((GU*)(unsigned long long)g,
                                   (LU*)(unsigned int)(unsigned long long)l,
                                   16, 0, 0);
}

// ---------------- dtype detection ----------------
__global__ void detect_kernel(const unsigned short* __restrict__ x, int* __restrict__ flag) {
  __shared__ int cnt;
  if (threadIdx.x == 0) cnt = 0;
  __syncthreads();
  unsigned int v = x[2 * threadIdx.x];
  unsigned int e = (v >> 7) & 0xFFu;
  int ok = (e >= 100u && e <= 135u) ? 1 : 0;
  atomicAdd(&cnt, ok);
  __syncthreads();
  if (threadIdx.x == 0) *flag = (cnt >= 128) ? 1 : 0;
}

// ---------------- x_in -> bf16 (GEMM1 A); residual read raw later ----------------
__global__ void convert_x_kernel(const void* __restrict__ src,
                                 unsigned short* __restrict__ dstb,
                                 const int* __restrict__ flag) {
  int c = blockIdx.x * blockDim.x + threadIdx.x;  // chunk of 8 elems
  int isbf = *flag;
  if (isbf) {
    ((uint4*)dstb)[c] = ((const uint4*)src)[c];
  } else {
    float4 a = ((const float4*)src)[2 * c];
    float4 b = ((const float4*)src)[2 * c + 1];
    uint4 p;
    p.x = (unsigned int)f2bf(a.x) | ((unsigned int)f2bf(a.y) << 16);
    p.y = (unsigned int)f2bf(a.z) | ((unsigned int)f2bf(a.w) << 16);
    p.z = (unsigned int)f2bf(b.x) | ((unsigned int)f2bf(b.y) << 16);
    p.w = (unsigned int)f2bf(b.z) | ((unsigned int)f2bf(b.w) << 16);
    ((uint4*)dstb)[c] = p;
  }
}

// ---------------- small vectors; A_log -> A2 = -exp(A_log)*log2(e) ----------------
__global__ void convert_smalls_kernel(const void* b_dt, const void* A_log, const void* Dp,
                                      const void* ln_g, const void* ln_b,
                                      float* o_bdt, float* o_a2, float* o_dp,
                                      float* o_lng, float* o_lnb,
                                      const int* __restrict__ flag) {
  int g = blockIdx.x * blockDim.x + threadIdx.x;  // 0..20479
  int isbf = *flag;
  if (g < 1024)              o_bdt[g]          = load_elem(b_dt, g, isbf);
  else if (g < 17408) {
    float v = load_elem(A_log, g - 1024, isbf);
    o_a2[g - 1024] = -expf(v) * 1.4426950408889634f;
  }
  else if (g < 18432)        o_dp[g - 17408]   = load_elem(Dp, g - 17408, isbf);
  else if (g < 19456)        o_lng[g - 18432]  = load_elem(ln_g, g - 18432, isbf);
  else                       o_lnb[g - 19456]  = load_elem(ln_b, g - 19456, isbf);
}

// ---------------- all 4 weight transposes in one launch (grid.z = op) ----------------
__global__ void transpose_all_kernel(const void* __restrict__ s0, const void* __restrict__ s1,
                                     const void* __restrict__ s2, const void* __restrict__ s3,
                                     unsigned short* __restrict__ d0, unsigned short* __restrict__ d1,
                                     unsigned short* __restrict__ d2, unsigned short* __restrict__ d3,
                                     const int* __restrict__ flag) {
  __shared__ float tile[32][33];
  const void* src; unsigned short* dst; int ncols, nx;
  switch (blockIdx.z) {
    case 0:  src = s0; dst = d0; ncols = 2048; nx = 64; break;
    case 1:  src = s1; dst = d1; ncols = 1056; nx = 33; break;
    case 2:  src = s2; dst = d2; ncols = 1024; nx = 32; break;
    default: src = s3; dst = d3; ncols = 1024; nx = 32; break;
  }
  if ((int)blockIdx.x >= nx) return;
  int tx = threadIdx.x, ty = threadIdx.y;   // 32 x 8
  int n0 = blockIdx.x * 32, k0 = blockIdx.y * 32;
  int isbf = *flag;
  #pragma unroll
  for (int r = 0; r < 4; ++r) {
    int k = k0 + ty + r * 8;
    int n = n0 + tx;
    float v = (n < ncols) ? load_elem(src, (size_t)k * ncols + n, isbf) : 0.f;
    tile[ty + r * 8][tx] = v;
  }
  __syncthreads();
  #pragma unroll
  for (int r = 0; r < 4; ++r) {
    int n = n0 + ty + r * 8;
    int k = k0 + tx;
    dst[(size_t)n * 1024 + k] = f2bf(tile[tx][ty + r * 8]);
  }
}

// ---------------- bf16 MFMA GEMM, 64x128 tile, dist-2 pipelined LDS-DMA staging ------
// A: bf16 Mx1024. Bt: bf16 Nx1024 (K contig, row stride ldb). 3 LDS stages x
// (A 4KB + B 8KB) = 36KB -> 4 blocks/CU. Per iter/wave: 3 staging instrs,
// s_waitcnt vmcnt(3) (stage k landed, k+1 in flight), s_barrier, issue k+2,
// 8 MFMA. One barrier per iter; loads stay in flight across it (R3-proven).
// MODE 1: n<1024 -> x_bf (bf16); else silu -> s_bf (bf16)          [N=2048]
// MODE 2: n<1024 -> draw_bf; <1040 B_ssm f32; <1056 C_ssm f32      [N=1152]
// MODE 3: o0 = softplus(v + aux[n]) bf16                           [N=1024]
// MODE 4: o0 = f32 (v + x_in[m,n]), x_in raw dtype via flag        [N=1024]
template<int MODE>
__global__ __launch_bounds__(256, 4) void gemm_bf(
    const unsigned short* __restrict__ A, const unsigned short* __restrict__ Bt, int ldb,
    void* __restrict__ o0, void* __restrict__ o1, void* __restrict__ o2,
    float* __restrict__ o3, float* __restrict__ o4,
    const float* __restrict__ aux, const void* __restrict__ auxv,
    const int* __restrict__ flag) {
  __shared__ __align__(16) unsigned short a_lds[3][64 * 32];    // 12 KB
  __shared__ __align__(16) unsigned short b_lds[3][128 * 32];   // 24 KB
  const int tid = threadIdx.x;
  const int m0 = blockIdx.x * 64, n0 = blockIdx.y * 128;
  const int wave = tid >> 6, lane = tid & 63;
  const int wr = (wave >> 1) * 32, wc = (wave & 1) * 64;   // wave -> 32x64 sub-tile
  const int lrow = lane & 15, quad = lane >> 4;

  // staging: lane l -> local row l>>2, 16B slot l&3 holding K-chunk
  // (l&3)^((l>>3)&3) (XOR swizzle; frag ds_read_b128 2-way aliased = free).
  const int sc = (lane & 3) ^ ((lane >> 3) & 3);
  const unsigned short* gA  = A  + (size_t)(m0 + wave * 16 + (lane >> 2)) * 1024 + sc * 8;
  const unsigned short* gB  = Bt + (size_t)(n0 + wave * 32 + (lane >> 2)) * ldb + sc * 8;
  const unsigned short* gB2 = gB + (size_t)16 * ldb;
  const int q2 = quad ^ ((lrow >> 1) & 3);

  f32x4 acc[2][4];
  #pragma unroll
  for (int i = 0; i < 2; ++i)
    #pragma unroll
    for (int j = 0; j < 4; ++j)
      #pragma unroll
      for (int r = 0; r < 4; ++r) acc[i][j][r] = 0.f;

  auto issue = [&](int k) {
    unsigned short* ab = a_lds[k % 3] + wave * 16 * 32;
    unsigned short* bb = b_lds[k % 3] + wave * 32 * 32;
    gload16(gA + k * 32, ab);
    gload16(gB + k * 32, bb);
    gload16(gB2 + k * 32, bb + 16 * 32);
  };
  auto compute = [&](int k) {
    const unsigned short* ard = a_lds[k % 3] + (wr + lrow) * 32 + q2 * 8;
    const unsigned short* brd = b_lds[k % 3] + (wc + lrow) * 32 + q2 * 8;
    bf16x8 af[2], bfr[4];
    #pragma unroll
    for (int i = 0; i < 2; ++i) af[i] = *(const bf16x8*)(ard + i * 16 * 32);
    #pragma unroll
    for (int j = 0; j < 4; ++j) bfr[j] = *(const bf16x8*)(brd + j * 16 * 32);
    #pragma unroll
    for (int i = 0; i < 2; ++i)
      #pragma unroll
      for (int j = 0; j < 4; ++j)
        acc[i][j] = __builtin_amdgcn_mfma_f32_16x16x32_bf16(af[i], bfr[j], acc[i][j], 0, 0, 0);
  };

  issue(0);
  issue(1);
  #pragma unroll
  for (int k = 0; k < 31; ++k) {
    asm volatile("s_waitcnt vmcnt(3)" ::: "memory");   // stage k landed
    __builtin_amdgcn_s_barrier();
    if (k + 2 < 32) issue(k + 2);
    compute(k);
  }
  asm volatile("s_waitcnt vmcnt(0)" ::: "memory");
  __builtin_amdgcn_s_barrier();
  compute(31);

  const int isbf = (MODE == 4) ? *flag : 0;

  // C/D layout: row = quad*4 + r, col = lane&15.
  #pragma unroll
  for (int i = 0; i < 2; ++i) {
    #pragma unroll
    for (int jj = 0; jj < 4; ++jj) {
      #pragma unroll
      for (int r = 0; r < 4; ++r) {
        int m = m0 + wr + i * 16 + quad * 4 + r;
        int n = n0 + wc + jj * 16 + lrow;
        float v = acc[i][jj][r];
        if (MODE == 1) {
          if (n < 1024) {
            ((unsigned short*)o0)[(size_t)m * 1024 + n] = f2bf(v);
          } else {
            float sig = 1.f / (1.f + expf(-v));
            ((unsigned short*)o1)[(size_t)m * 1024 + (n - 1024)] = f2bf(v * sig);
          }
        } else if (MODE == 2) {
          if (n < 1024)       ((unsigned short*)o0)[(size_t)m * 1024 + n] = f2bf(v);
          else if (n < 1040)  o3[(size_t)m * D_STATE + (n - 1024)] = v;
          else if (n < 1056)  o4[(size_t)m * D_STATE + (n - 1040)] = v;
          // n >= 1056: zero-padded columns, discard
        } else if (MODE == 3) {
          float t = v + aux[n];
          float sp = (t > 20.f) ? t : log1pf(expf(t));
          ((unsigned short*)o0)[(size_t)m * 1024 + n] = f2bf(sp);
        } else {  // MODE 4: residual from raw x_in
          ((float*)o0)[(size_t)m * 1024 + n] =
              v + load_elem(auxv, (size_t)m * 1024 + n, isbf);
        }
      }
    }
  }
}

// ---------------- chunked parallel scan (NSEG=64, LSEG=16) ----------------
// Channel = (b,d); thread holds h[0..15] in registers.
// PHASE 0: from h=0, produce H (final h) + sum(delta) per segment.
// PHASE 1: from h=hinit, produce g = (y + x*D)*silu(z), bf16.
template<int PHASE>
__global__ __launch_bounds__(256) void scan_phase(
    const unsigned short* __restrict__ dl_bf, const unsigned short* __restrict__ x_bf,
    const unsigned short* __restrict__ z_bf, const float* __restrict__ Bs,
    const float* __restrict__ Cs, const float* __restrict__ A2g,
    const float* __restrict__ Dpar, const float* __restrict__ hinit,
    float* __restrict__ Hout, float* __restrict__ sdout,
    unsigned short* __restrict__ g) {
  __shared__ float4 bsh[LSEG][4];
  __shared__ float4 csh[LSEG][4];
  const int tid = threadIdx.x;
  const int bid = blockIdx.x;                 // seg(64) x b(4) x dchunk(4) = 1024
  const int seg = bid >> 4;
  const int b = (bid >> 2) & 3;
  const int dc = bid & 3;
  const int d = dc * 256 + tid;
  const int t0 = seg * LSEG;
  const int bd = b * D_MODEL + d;

  if (tid < LSEG * 4) {                       // stage B (and C) segment rows
    int r = tid >> 2, q = tid & 3;
    size_t src = ((size_t)b * SEQ_L + t0 + r) * 4 + q;
    bsh[r][q] = ((const float4*)Bs)[src];
    if (PHASE == 1) csh[r][q] = ((const float4*)Cs)[src];
  }

  float A2r[16];
  {
    const float4* a4 = (const float4*)(A2g + (size_t)d * 16);
    #pragma unroll
    for (int q = 0; q < 4; ++q) {
      float4 v = a4[q];
      A2r[4*q] = v.x; A2r[4*q+1] = v.y; A2r[4*q+2] = v.z; A2r[4*q+3] = v.w;
    }
  }
  float h[16];
  if (PHASE == 1) {
    const float4* h4 = (const float4*)(hinit + (((size_t)seg * 4096) + bd) * 16);
    #pragma unroll
    for (int q = 0; q < 4; ++q) {
      float4 v = h4[q];
      h[4*q] = v.x; h[4*q+1] = v.y; h[4*q+2] = v.z; h[4*q+3] = v.w;
    }
  } else {
    #pragma unroll
    for (int n = 0; n < 16; ++n) h[n] = 0.f;
  }
  const float Dpd = (PHASE == 1) ? Dpar[d] : 0.f;
  float sd = 0.f;
  const size_t base = ((size_t)b * SEQ_L + t0) * D_MODEL + d;
  __syncthreads();

  unsigned short dreg[2][8], xreg[2][8], zreg[2][8];
  #pragma unroll
  for (int t = 0; t < 8; ++t) {
    size_t o = base + (size_t)t * D_MODEL;
    dreg[0][t] = dl_bf[o]; xreg[0][t] = x_bf[o];
    if (PHASE == 1) zreg[0][t] = z_bf[o];
  }
  #pragma unroll
  for (int c = 0; c < LSEG / 8; ++c) {
    const int cur = c & 1, nxt = cur ^ 1;
    if (c < LSEG / 8 - 1) {                   // prefetch next 8 steps
      #pragma unroll
      for (int t = 0; t < 8; ++t) {
        size_t o = base + (size_t)((c + 1) * 8 + t) * D_MODEL;
        dreg[nxt][t] = dl_bf[o]; xreg[nxt][t] = x_bf[o];
        if (PHASE == 1) zreg[nxt][t] = z_bf[o];
      }
    }
    #pragma unroll
    for (int t = 0; t < 8; ++t) {
      const int tt = c * 8 + t;
      float dl = bf2f(dreg[cur][t]);
      float xx = bf2f(xreg[cur][t]);
      float dx = dl * xx;
      sd += dl;
      float4 b0 = bsh[tt][0], b1 = bsh[tt][1], b2 = bsh[tt][2], b3 = bsh[tt][3];
      float bb[16] = {b0.x,b0.y,b0.z,b0.w, b1.x,b1.y,b1.z,b1.w,
                      b2.x,b2.y,b2.z,b2.w, b3.x,b3.y,b3.z,b3.w};
      if (PHASE == 0) {
        #pragma unroll
        for (int n = 0; n < 16; ++n) {
          float dA = exp2f(dl * A2r[n]);
          h[n] = fmaf(dA, h[n], dx * bb[n]);
        }
      } else {
        float4 c0 = csh[tt][0], c1 = csh[tt][1], c2 = csh[tt][2], c3 = csh[tt][3];
        float cc[16] = {c0.x,c0.y,c0.z,c0.w, c1.x,c1.y,c1.z,c1.w,
                        c2.x,c2.y,c2.z,c2.w, c3.x,c3.y,c3.z,c3.w};
        float y = 0.f;
        #pragma unroll
        for (int n = 0; n < 16; ++n) {
          float dA = exp2f(dl * A2r[n]);
          h[n] = fmaf(dA, h[n], dx * bb[n]);
          y = fmaf(h[n], cc[n], y);
        }
        float zz = bf2f(zreg[cur][t]);
        g[base + (size_t)tt * D_MODEL] = f2bf(fmaf(xx, Dpd, y) * zz);
      }
    }
  }
  if (PHASE == 0) {
    float4* ho = (float4*)(Hout + (((size_t)seg * 4096) + bd) * 16);
    #pragma unroll
    for (int q = 0; q < 4; ++q)
      ho[q] = make_float4(h[4*q], h[4*q+1], h[4*q+2], h[4*q+3]);
    sdout[(size_t)seg * 4096 + bd] = sd;
  }
}

// segment-level scan: h_init(s) = P(s-1)*h_init(s-1) + H(s-1), P = exp2(A2*sumdelta)
__global__ __launch_bounds__(256) void scan_phaseB(
    const float* __restrict__ H, const float* __restrict__ sdelta,
    const float* __restrict__ A2g, float* __restrict__ hinit) {
  int gidx = blockIdx.x * 256 + threadIdx.x;   // 65536 = bd(4096) x n(16)
  int bd = gidx >> 4, n = gidx & 15;
  float A2 = A2g[(size_t)(bd & (D_MODEL - 1)) * 16 + n];
  float hp = 0.f;
  for (int s = 0; s < NSEG; ++s) {
    size_t idx = ((size_t)s * 4096 + bd) * 16 + n;
    hinit[idx] = hp;
    float P = exp2f(A2 * sdelta[(size_t)s * 4096 + bd]);
    hp = fmaf(P, hp, H[idx]);
  }
}

// ---------------- LayerNorm over D=1024 per row ----------------
__global__ __launch_bounds__(256) void ln_kernel(const float* __restrict__ res,
    const float* __restrict__ lng, const float* __restrict__ lnb,
    void* __restrict__ out, const int* __restrict__ flag) {
  int row = blockIdx.x, tid = threadIdx.x;
  const float4* r4 = (const float4*)(res + (size_t)row * D_MODEL);
  float4 v = r4[tid];
  float s = v.x + v.y + v.z + v.w;
  float q = v.x * v.x + v.y * v.y + v.z * v.z + v.w * v.w;
  #pragma unroll
  for (int m = 1; m < 64; m <<= 1) { s += __shfl_xor(s, m); q += __shfl_xor(q, m); }
  __shared__ float ss[4], qs[4];
  int w = tid >> 6;
  if ((tid & 63) == 0) { ss[w] = s; qs[w] = q; }
  __syncthreads();
  s = ss[0] + ss[1] + ss[2] + ss[3];
  q = qs[0] + qs[1] + qs[2] + qs[3];
  float mu = s * (1.f / D_MODEL);
  float var = q * (1.f / D_MODEL) - mu * mu;
  float rstd = rsqrtf(var + 1e-5f);
  float4 gg = ((const float4*)lng)[tid];
  float4 bb = ((const float4*)lnb)[tid];
  float o0 = (v.x - mu) * rstd * gg.x + bb.x;
  float o1 = (v.y - mu) * rstd * gg.y + bb.y;
  float o2 = (v.z - mu) * rstd * gg.z + bb.z;
  float o3 = (v.w - mu) * rstd * gg.w + bb.w;
  if (*flag) {
    ushort4 pv;
    pv.x = f2bf(o0); pv.y = f2bf(o1); pv.z = f2bf(o2); pv.w = f2bf(o3);
    ((ushort4*)out)[(size_t)row * 256 + tid] = pv;
  } else {
    ((float4*)out)[(size_t)row * 256 + tid] = make_float4(o0, o1, o2, o3);
  }
}

extern "C" void kernel_launch(void* const* d_in, const int* in_sizes, int n_in,
                              void* d_out, int out_size, void* d_ws, size_t ws_size,
                              hipStream_t stream) {
  (void)in_sizes; (void)n_in; (void)out_size; (void)ws_size;
  const void* x_in  = d_in[0];
  const void* W_in  = d_in[1];
  const void* W_x   = d_in[2];
  const void* W_dt  = d_in[3];
  const void* b_dt  = d_in[4];
  const void* A_log = d_in[5];
  const void* D_par = d_in[6];
  const void* W_out = d_in[7];
  const void* ln_g  = d_in[8];
  const void* ln_b  = d_in[9];

  char* ws = (char*)d_ws;
  size_t off = 0;
  auto alloc = [&](size_t bytes) -> void* {
    void* p = ws + off;
    off += (bytes + 255) & ~(size_t)255;
    return p;
  };
  int* flag               = (int*)alloc(16);
  unsigned short* x_in_b  = (unsigned short*)alloc((size_t)M_ROWS * D_MODEL * 2);
  float* bdt_f            = (float*)alloc(1024 * 4);
  float* a2_f             = (float*)alloc(16384 * 4);
  float* dp_f             = (float*)alloc(1024 * 4);
  float* lng_f            = (float*)alloc(1024 * 4);
  float* lnb_f            = (float*)alloc(1024 * 4);
  unsigned short* wt_in   = (unsigned short*)alloc((size_t)2048 * 1024 * 2);
  unsigned short* wt_x    = (unsigned short*)alloc((size_t)1152 * 1024 * 2);
  unsigned short* wt_dt   = (unsigned short*)alloc((size_t)1024 * 1024 * 2);
  unsigned short* wt_out  = (unsigned short*)alloc((size_t)1024 * 1024 * 2);
  unsigned short* x_bf    = (unsigned short*)alloc((size_t)M_ROWS * D_MODEL * 2);
  unsigned short* s_bf    = (unsigned short*)alloc((size_t)M_ROWS * D_MODEL * 2);  // silu(z)
  unsigned short* draw_bf = (unsigned short*)alloc((size_t)M_ROWS * D_MODEL * 2);
  unsigned short* delta_bf= (unsigned short*)alloc((size_t)M_ROWS * D_MODEL * 2);
  float* bssm_f           = (float*)alloc((size_t)M_ROWS * D_STATE * 4);
  float* cssm_f           = (float*)alloc((size_t)M_ROWS * D_STATE * 4);
  float* H_f              = (float*)alloc((size_t)NSEG * 4096 * 16 * 4);
  float* hinit_f          = (float*)alloc((size_t)NSEG * 4096 * 16 * 4);
  float* sdelta_f         = (float*)alloc((size_t)NSEG * 4096 * 4);
  unsigned short* g_bf = draw_bf;  // alias: draw consumed by G3 before scan1 writes g
  float* res_f = (float*)x_bf;     // alias: x_bf+s_bf (16MB contiguous) consumed by scan1
                                   // before G4 writes res

  detect_kernel<<<1, 256, 0, stream>>>((const unsigned short*)x_in, flag);
  convert_x_kernel<<<2048, 256, 0, stream>>>(x_in, x_in_b, flag);
  convert_smalls_kernel<<<80, 256, 0, stream>>>(b_dt, A_log, D_par, ln_g, ln_b,
                                                bdt_f, a2_f, dp_f, lng_f, lnb_f, flag);
  dim3 tb(32, 8);
  transpose_all_kernel<<<dim3(64, 32, 4), tb, 0, stream>>>(
      W_in, W_x, W_dt, W_out, wt_in, wt_x, wt_dt, wt_out, flag);

  gemm_bf<1><<<dim3(64, 16), 256, 0, stream>>>(x_in_b, wt_in, 1024,
      x_bf, s_bf, nullptr, nullptr, nullptr, nullptr, nullptr, flag);
  gemm_bf<2><<<dim3(64, 9), 256, 0, stream>>>(x_bf, wt_x, 1024,
      draw_bf, nullptr, nullptr, bssm_f, cssm_f, nullptr, nullptr, flag);
  gemm_bf<3><<<dim3(64, 8), 256, 0, stream>>>(draw_bf, wt_dt, 1024,
      delta_bf, nullptr, nullptr, nullptr, nullptr, bdt_f, nullptr, flag);

  scan_phase<0><<<1024, 256, 0, stream>>>(delta_bf, x_bf, nullptr, bssm_f, nullptr,
                                          a2_f, nullptr, nullptr, H_f, sdelta_f, nullptr);
  scan_phaseB<<<256, 256, 0, stream>>>(H_f, sdelta_f, a2_f, hinit_f);
  scan_phase<1><<<1024, 256, 0, stream>>>(delta_bf, x_bf, s_bf, bssm_f, cssm_f,
                                          a2_f, dp_f, hinit_f, nullptr, nullptr, g_bf);

  gemm_bf<4><<<dim3(64, 8), 256, 0, stream>>>(g_bf, wt_out, 1024,
      res_f, nullptr, nullptr, nullptr, nullptr, nullptr, x_in, flag);
  ln_kernel<<<4096, 256, 0, stream>>>(res_f, lng_f, lnb_f, d_out, flag);
}

// Round 8
// 266.341 us; speedup vs baseline: 1.5800x; 1.0497x over previous
//
#include <hip/hip_runtime.h>

#define D_MODEL 1024
#define D_STATE 16
#define M_ROWS  4096   // B*L
#define SEQ_L   1024
#define NSEG    64
#define LSEG    16     // SEQ_L / NSEG

typedef __bf16 bf16x8 __attribute__((ext_vector_type(8)));
typedef float  f32x4  __attribute__((ext_vector_type(4)));

__device__ __forceinline__ unsigned short f2bf(float f) {
  unsigned int u = __builtin_bit_cast(unsigned int, f);
  u += 0x7fffu + ((u >> 16) & 1u);           // RNE
  return (unsigned short)(u >> 16);
}
__device__ __forceinline__ float bf2f(unsigned short b) {
  unsigned int u = ((unsigned int)b) << 16;
  return __builtin_bit_cast(float, u);
}
__device__ __forceinline__ float load_elem(const void* p, size_t i, int isbf) {
  if (isbf) return bf2f(((const unsigned short*)p)[i]);
  return ((const float*)p)[i];
}

// Decentralized dtype detection: 64 samples of x_in's even u16s per wave.
// bf16 N(0,1): exponent field in [100,135] for all 64 lanes; fp32 low-mantissa
// u16s: ~uniform, ~9/64 in range. Threshold 32. Wave-uniform result.
__device__ __forceinline__ int is_bf16(const void* x_in) {
  unsigned int v = ((const unsigned short*)x_in)[2 * (threadIdx.x & 63)];
  unsigned int e = (v >> 7) & 0xFFu;
  unsigned long long m = __ballot(e >= 100u && e <= 135u);
  return __popcll(m) >= 32;
}

// async global->LDS, 16B per lane. LDS dest = (wave-uniform base) + lane*16.
__device__ __forceinline__ void gload16(const void* g, void* l) {
  typedef const __attribute__((address_space(1))) unsigned int GU;
  typedef __attribute__((address_space(3))) unsigned int LU;
  __builtin_amdgcn_global_load_lds((GU*)(unsigned long long)g,
                                   (LU*)(unsigned int)(unsigned long long)l,
                                   16, 0, 0);
}

// ---------------- merged converts: x_in -> bf16, W_x -> bf16 raw, smalls ----------------
__global__ void convert_kernel(const void* __restrict__ x_in,
                               unsigned short* __restrict__ x_b,
                               const void* __restrict__ W_x,
                               unsigned short* __restrict__ wx_raw,
                               const void* b_dt, const void* A_log, const void* Dp,
                               const void* ln_g, const void* ln_b,
                               float* o_bdt, float* o_a2, float* o_dp,
                               float* o_lng, float* o_lnb) {
  const int isbf = is_bf16(x_in);
  const int bid = blockIdx.x;
  if (bid < 2048 || bid >= 2128) {           // bulk bf16 conversion, 8 elems/thread
    const void* src; unsigned short* dst; int c;
    if (bid < 2048) { src = x_in; dst = x_b; c = bid * 256 + threadIdx.x; }
    else { src = W_x; dst = wx_raw; c = (bid - 2128) * 256 + threadIdx.x; }  // 135168 chunks
    if (isbf) {
      ((uint4*)dst)[c] = ((const uint4*)src)[c];
    } else {
      float4 a = ((const float4*)src)[2 * c];
      float4 b = ((const float4*)src)[2 * c + 1];
      uint4 p;
      p.x = (unsigned int)f2bf(a.x) | ((unsigned int)f2bf(a.y) << 16);
      p.y = (unsigned int)f2bf(a.z) | ((unsigned int)f2bf(a.w) << 16);
      p.z = (unsigned int)f2bf(b.x) | ((unsigned int)f2bf(b.y) << 16);
      p.w = (unsigned int)f2bf(b.z) | ((unsigned int)f2bf(b.w) << 16);
      ((uint4*)dst)[c] = p;
    }
  } else {                                   // smalls: 80 blocks, g in 0..20479
    int g = (bid - 2048) * 256 + threadIdx.x;
    if (g < 1024)              o_bdt[g]          = load_elem(b_dt, g, isbf);
    else if (g < 17408) {
      float v = load_elem(A_log, g - 1024, isbf);
      o_a2[g - 1024] = -expf(v) * 1.4426950408889634f;
    }
    else if (g < 18432)        o_dp[g - 17408]   = load_elem(Dp, g - 17408, isbf);
    else if (g < 19456)        o_lng[g - 18432]  = load_elem(ln_g, g - 18432, isbf);
    else                       o_lnb[g - 19456]  = load_elem(ln_b, g - 19456, isbf);
  }
}

// ---------------- weight transposes in one launch (grid.z = op) ----------------
// z=0: W_in (1024x2048) -> wt_in (2048x1024)
// z=1: W_x cols 1024..1151 -> wt_xbc (128x1024), cols >=1056 zero-padded
// z=2: W_dt -> wt_dt; z=3: W_out -> wt_out
__global__ void transpose_all_kernel(const void* __restrict__ s0, const void* __restrict__ s1,
                                     const void* __restrict__ s2, const void* __restrict__ s3,
                                     unsigned short* __restrict__ d0, unsigned short* __restrict__ d1,
                                     unsigned short* __restrict__ d2, unsigned short* __restrict__ d3,
                                     const void* __restrict__ x_in) {
  __shared__ float tile[32][33];
  const int isbf = is_bf16(x_in);
  const void* src; unsigned short* dst; int ncols, col0, nx;
  switch (blockIdx.z) {
    case 0:  src = s0; dst = d0; ncols = 2048; col0 = 0;    nx = 64; break;
    case 1:  src = s1; dst = d1; ncols = 1056; col0 = 1024; nx = 4;  break;
    case 2:  src = s2; dst = d2; ncols = 1024; col0 = 0;    nx = 32; break;
    default: src = s3; dst = d3; ncols = 1024; col0 = 0;    nx = 32; break;
  }
  if ((int)blockIdx.x >= nx) return;
  int tx = threadIdx.x, ty = threadIdx.y;   // 32 x 8
  int n0 = col0 + blockIdx.x * 32, k0 = blockIdx.y * 32;
  #pragma unroll
  for (int r = 0; r < 4; ++r) {
    int k = k0 + ty + r * 8;
    int n = n0 + tx;
    float v = (n < ncols) ? load_elem(src, (size_t)k * ncols + n, isbf) : 0.f;
    tile[ty + r * 8][tx] = v;
  }
  __syncthreads();
  #pragma unroll
  for (int r = 0; r < 4; ++r) {
    int n = n0 + ty + r * 8;
    int k = k0 + tx;
    dst[(size_t)(n - col0) * 1024 + k] = f2bf(tile[tx][ty + r * 8]);
  }
}

// ---------------- bf16 MFMA GEMM, 64x128 tile, dist-2 pipelined LDS-DMA (R7-proven) ---
// MODE 0: o0 = bf16 C (ldc 1024)                              [W_delta composition]
// MODE 1: n<1024 -> x_bf; else silu -> s_bf (both bf16)       [N=2048]
// MODE 2: n<1024 -> softplus(v+aux[n]) -> delta_bf; n<1040 -> B f32; n<1056 -> C f32.
//         by==8 reads Bt2 (o2) rows n-1024.                   [N=1152 grid, 1056 used]
// MODE 4: o0 = f32 (v + x_in[m,n]), x_in raw (auxv), self-detected dtype
template<int MODE>
__global__ __launch_bounds__(256, 4) void gemm_bf(
    const unsigned short* __restrict__ A, const unsigned short* __restrict__ Bt, int ldb,
    void* __restrict__ o0, void* __restrict__ o1, void* __restrict__ o2,
    float* __restrict__ o3, float* __restrict__ o4,
    const float* __restrict__ aux, const void* __restrict__ auxv) {
  __shared__ __align__(16) unsigned short a_lds[3][64 * 32];    // 12 KB
  __shared__ __align__(16) unsigned short b_lds[3][128 * 32];   // 24 KB
  const int isbf = (MODE == 4) ? is_bf16(auxv) : 0;
  const int tid = threadIdx.x;
  const int m0 = blockIdx.x * 64, n0 = blockIdx.y * 128;
  const int wave = tid >> 6, lane = tid & 63;
  const int wr = (wave >> 1) * 32, wc = (wave & 1) * 64;   // wave -> 32x64 sub-tile
  const int lrow = lane & 15, quad = lane >> 4;

  const unsigned short* Bsrc = Bt;
  int nb0 = n0;
  if (MODE == 2 && n0 >= 1024) { Bsrc = (const unsigned short*)o2; nb0 = n0 - 1024; }

  // staging: lane l -> local row l>>2, 16B slot l&3 holding K-chunk
  // (l&3)^((l>>3)&3) (XOR swizzle; frag ds_read_b128 2-way aliased = free).
  const int sc = (lane & 3) ^ ((lane >> 3) & 3);
  const unsigned short* gA  = A    + (size_t)(m0 + wave * 16 + (lane >> 2)) * 1024 + sc * 8;
  const unsigned short* gB  = Bsrc + (size_t)(nb0 + wave * 32 + (lane >> 2)) * ldb + sc * 8;
  const unsigned short* gB2 = gB + (size_t)16 * ldb;
  const int q2 = quad ^ ((lrow >> 1) & 3);

  f32x4 acc[2][4];
  #pragma unroll
  for (int i = 0; i < 2; ++i)
    #pragma unroll
    for (int j = 0; j < 4; ++j)
      #pragma unroll
      for (int r = 0; r < 4; ++r) acc[i][j][r] = 0.f;

  auto issue = [&](int k) {
    unsigned short* ab = a_lds[k % 3] + wave * 16 * 32;
    unsigned short* bb = b_lds[k % 3] + wave * 32 * 32;
    gload16(gA + k * 32, ab);
    gload16(gB + k * 32, bb);
    gload16(gB2 + k * 32, bb + 16 * 32);
  };
  auto compute = [&](int k) {
    const unsigned short* ard = a_lds[k % 3] + (wr + lrow) * 32 + q2 * 8;
    const unsigned short* brd = b_lds[k % 3] + (wc + lrow) * 32 + q2 * 8;
    bf16x8 af[2], bfr[4];
    #pragma unroll
    for (int i = 0; i < 2; ++i) af[i] = *(const bf16x8*)(ard + i * 16 * 32);
    #pragma unroll
    for (int j = 0; j < 4; ++j) bfr[j] = *(const bf16x8*)(brd + j * 16 * 32);
    #pragma unroll
    for (int i = 0; i < 2; ++i)
      #pragma unroll
      for (int j = 0; j < 4; ++j)
        acc[i][j] = __builtin_amdgcn_mfma_f32_16x16x32_bf16(af[i], bfr[j], acc[i][j], 0, 0, 0);
  };

  issue(0);
  issue(1);
  #pragma unroll
  for (int k = 0; k < 31; ++k) {
    asm volatile("s_waitcnt vmcnt(3)" ::: "memory");   // stage k landed, k+1 in flight
    __builtin_amdgcn_s_barrier();
    if (k + 2 < 32) issue(k + 2);
    compute(k);
  }
  asm volatile("s_waitcnt vmcnt(0)" ::: "memory");
  __builtin_amdgcn_s_barrier();
  compute(31);

  // C/D layout: row = quad*4 + r, col = lane&15.
  #pragma unroll
  for (int i = 0; i < 2; ++i) {
    #pragma unroll
    for (int jj = 0; jj < 4; ++jj) {
      #pragma unroll
      for (int r = 0; r < 4; ++r) {
        int m = m0 + wr + i * 16 + quad * 4 + r;
        int n = n0 + wc + jj * 16 + lrow;
        float v = acc[i][jj][r];
        if (MODE == 0) {
          ((unsigned short*)o0)[(size_t)m * 1024 + n] = f2bf(v);
        } else if (MODE == 1) {
          if (n < 1024) {
            ((unsigned short*)o0)[(size_t)m * 1024 + n] = f2bf(v);
          } else {
            float sig = 1.f / (1.f + expf(-v));
            ((unsigned short*)o1)[(size_t)m * 1024 + (n - 1024)] = f2bf(v * sig);
          }
        } else if (MODE == 2) {
          if (n < 1024) {
            float t = v + aux[n];
            float sp = (t > 20.f) ? t : log1pf(expf(t));
            ((unsigned short*)o0)[(size_t)m * 1024 + n] = f2bf(sp);
          }
          else if (n < 1040)  o3[(size_t)m * D_STATE + (n - 1024)] = v;
          else if (n < 1056)  o4[(size_t)m * D_STATE + (n - 1040)] = v;
          // n >= 1056: zero-padded columns, discard
        } else {  // MODE 4: residual from raw x_in
          ((float*)o0)[(size_t)m * 1024 + n] =
              v + load_elem(auxv, (size_t)m * 1024 + n, isbf);
        }
      }
    }
  }
}

// ---------------- chunked parallel scan (NSEG=64, LSEG=16) ----------------
template<int PHASE>
__global__ __launch_bounds__(256) void scan_phase(
    const unsigned short* __restrict__ dl_bf, const unsigned short* __restrict__ x_bf,
    const unsigned short* __restrict__ z_bf, const float* __restrict__ Bs,
    const float* __restrict__ Cs, const float* __restrict__ A2g,
    const float* __restrict__ Dpar, const float* __restrict__ hinit,
    float* __restrict__ Hout, float* __restrict__ sdout,
    unsigned short* __restrict__ g) {
  __shared__ float4 bsh[LSEG][4];
  __shared__ float4 csh[LSEG][4];
  const int tid = threadIdx.x;
  const int bid = blockIdx.x;                 // seg(64) x b(4) x dchunk(4) = 1024
  const int seg = bid >> 4;
  const int b = (bid >> 2) & 3;
  const int dc = bid & 3;
  const int d = dc * 256 + tid;
  const int t0 = seg * LSEG;
  const int bd = b * D_MODEL + d;

  if (tid < LSEG * 4) {                       // stage B (and C) segment rows
    int r = tid >> 2, q = tid & 3;
    size_t src = ((size_t)b * SEQ_L + t0 + r) * 4 + q;
    bsh[r][q] = ((const float4*)Bs)[src];
    if (PHASE == 1) csh[r][q] = ((const float4*)Cs)[src];
  }

  float A2r[16];
  {
    const float4* a4 = (const float4*)(A2g + (size_t)d * 16);
    #pragma unroll
    for (int q = 0; q < 4; ++q) {
      float4 v = a4[q];
      A2r[4*q] = v.x; A2r[4*q+1] = v.y; A2r[4*q+2] = v.z; A2r[4*q+3] = v.w;
    }
  }
  float h[16];
  if (PHASE == 1) {
    const float4* h4 = (const float4*)(hinit + (((size_t)seg * 4096) + bd) * 16);
    #pragma unroll
    for (int q = 0; q < 4; ++q) {
      float4 v = h4[q];
      h[4*q] = v.x; h[4*q+1] = v.y; h[4*q+2] = v.z; h[4*q+3] = v.w;
    }
  } else {
    #pragma unroll
    for (int n = 0; n < 16; ++n) h[n] = 0.f;
  }
  const float Dpd = (PHASE == 1) ? Dpar[d] : 0.f;
  float sd = 0.f;
  const size_t base = ((size_t)b * SEQ_L + t0) * D_MODEL + d;
  __syncthreads();

  unsigned short dreg[2][8], xreg[2][8], zreg[2][8];
  #pragma unroll
  for (int t = 0; t < 8; ++t) {
    size_t o = base + (size_t)t * D_MODEL;
    dreg[0][t] = dl_bf[o]; xreg[0][t] = x_bf[o];
    if (PHASE == 1) zreg[0][t] = z_bf[o];
  }
  #pragma unroll
  for (int c = 0; c < LSEG / 8; ++c) {
    const int cur = c & 1, nxt = cur ^ 1;
    if (c < LSEG / 8 - 1) {                   // prefetch next 8 steps
      #pragma unroll
      for (int t = 0; t < 8; ++t) {
        size_t o = base + (size_t)((c + 1) * 8 + t) * D_MODEL;
        dreg[nxt][t] = dl_bf[o]; xreg[nxt][t] = x_bf[o];
        if (PHASE == 1) zreg[nxt][t] = z_bf[o];
      }
    }
    #pragma unroll
    for (int t = 0; t < 8; ++t) {
      const int tt = c * 8 + t;
      float dl = bf2f(dreg[cur][t]);
      float xx = bf2f(xreg[cur][t]);
      float dx = dl * xx;
      sd += dl;
      float4 b0 = bsh[tt][0], b1 = bsh[tt][1], b2 = bsh[tt][2], b3 = bsh[tt][3];
      float bb[16] = {b0.x,b0.y,b0.z,b0.w, b1.x,b1.y,b1.z,b1.w,
                      b2.x,b2.y,b2.z,b2.w, b3.x,b3.y,b3.z,b3.w};
      if (PHASE == 0) {
        #pragma unroll
        for (int n = 0; n < 16; ++n) {
          float dA = exp2f(dl * A2r[n]);
          h[n] = fmaf(dA, h[n], dx * bb[n]);
        }
      } else {
        float4 c0 = csh[tt][0], c1 = csh[tt][1], c2 = csh[tt][2], c3 = csh[tt][3];
        float cc[16] = {c0.x,c0.y,c0.z,c0.w, c1.x,c1.y,c1.z,c1.w,
                        c2.x,c2.y,c2.z,c2.w, c3.x,c3.y,c3.z,c3.w};
        float y = 0.f;
        #pragma unroll
        for (int n = 0; n < 16; ++n) {
          float dA = exp2f(dl * A2r[n]);
          h[n] = fmaf(dA, h[n], dx * bb[n]);
          y = fmaf(h[n], cc[n], y);
        }
        float zz = bf2f(zreg[cur][t]);
        g[base + (size_t)tt * D_MODEL] = f2bf(fmaf(xx, Dpd, y) * zz);
      }
    }
  }
  if (PHASE == 0) {
    float4* ho = (float4*)(Hout + (((size_t)seg * 4096) + bd) * 16);
    #pragma unroll
    for (int q = 0; q < 4; ++q)
      ho[q] = make_float4(h[4*q], h[4*q+1], h[4*q+2], h[4*q+3]);
    sdout[(size_t)seg * 4096 + bd] = sd;
  }
}

// segment-level scan: h_init(s) = P(s-1)*h_init(s-1) + H(s-1), P = exp2(A2*sumdelta)
__global__ __launch_bounds__(256) void scan_phaseB(
    const float* __restrict__ H, const float* __restrict__ sdelta,
    const float* __restrict__ A2g, float* __restrict__ hinit) {
  int gidx = blockIdx.x * 256 + threadIdx.x;   // 65536 = bd(4096) x n(16)
  int bd = gidx >> 4, n = gidx & 15;
  float A2 = A2g[(size_t)(bd & (D_MODEL - 1)) * 16 + n];
  float hp = 0.f;
  #pragma unroll 8
  for (int s = 0; s < NSEG; ++s) {
    size_t idx = ((size_t)s * 4096 + bd) * 16 + n;
    hinit[idx] = hp;
    float P = exp2f(A2 * sdelta[(size_t)s * 4096 + bd]);
    hp = fmaf(P, hp, H[idx]);
  }
}

// ---------------- LayerNorm over D=1024 per row ----------------
__global__ __launch_bounds__(256) void ln_kernel(const float* __restrict__ res,
    const float* __restrict__ lng, const float* __restrict__ lnb,
    void* __restrict__ out, const void* __restrict__ x_in) {
  const int isbf = is_bf16(x_in);
  int row = blockIdx.x, tid = threadIdx.x;
  const float4* r4 = (const float4*)(res + (size_t)row * D_MODEL);
  float4 v = r4[tid];
  float s = v.x + v.y + v.z + v.w;
  float q = v.x * v.x + v.y * v.y + v.z * v.z + v.w * v.w;
  #pragma unroll
  for (int m = 1; m < 64; m <<= 1) { s += __shfl_xor(s, m); q += __shfl_xor(q, m); }
  __shared__ float ss[4], qs[4];
  int w = tid >> 6;
  if ((tid & 63) == 0) { ss[w] = s; qs[w] = q; }
  __syncthreads();
  s = ss[0] + ss[1] + ss[2] + ss[3];
  q = qs[0] + qs[1] + qs[2] + qs[3];
  float mu = s * (1.f / D_MODEL);
  float var = q * (1.f / D_MODEL) - mu * mu;
  float rstd = rsqrtf(var + 1e-5f);
  float4 gg = ((const float4*)lng)[tid];
  float4 bb = ((const float4*)lnb)[tid];
  float o0 = (v.x - mu) * rstd * gg.x + bb.x;
  float o1 = (v.y - mu) * rstd * gg.y + bb.y;
  float o2 = (v.z - mu) * rstd * gg.z + bb.z;
  float o3 = (v.w - mu) * rstd * gg.w + bb.w;
  if (isbf) {
    ushort4 pv;
    pv.x = f2bf(o0); pv.y = f2bf(o1); pv.z = f2bf(o2); pv.w = f2bf(o3);
    ((ushort4*)out)[(size_t)row * 256 + tid] = pv;
  } else {
    ((float4*)out)[(size_t)row * 256 + tid] = make_float4(o0, o1, o2, o3);
  }
}

extern "C" void kernel_launch(void* const* d_in, const int* in_sizes, int n_in,
                              void* d_out, int out_size, void* d_ws, size_t ws_size,
                              hipStream_t stream) {
  (void)in_sizes; (void)n_in; (void)out_size; (void)ws_size;
  const void* x_in  = d_in[0];
  const void* W_in  = d_in[1];
  const void* W_x   = d_in[2];
  const void* W_dt  = d_in[3];
  const void* b_dt  = d_in[4];
  const void* A_log = d_in[5];
  const void* D_par = d_in[6];
  const void* W_out = d_in[7];
  const void* ln_g  = d_in[8];
  const void* ln_b  = d_in[9];

  char* ws = (char*)d_ws;
  size_t off = 0;
  auto alloc = [&](size_t bytes) -> void* {
    void* p = ws + off;
    off += (bytes + 255) & ~(size_t)255;
    return p;
  };
  unsigned short* x_in_b  = (unsigned short*)alloc((size_t)M_ROWS * D_MODEL * 2);
  unsigned short* wx_raw  = (unsigned short*)alloc((size_t)1024 * 1056 * 2);  // W_x bf16 raw
  float* bdt_f            = (float*)alloc(1024 * 4);
  float* a2_f             = (float*)alloc(16384 * 4);
  float* dp_f             = (float*)alloc(1024 * 4);
  float* lng_f            = (float*)alloc(1024 * 4);
  float* lnb_f            = (float*)alloc(1024 * 4);
  unsigned short* wt_in   = (unsigned short*)alloc((size_t)2048 * 1024 * 2);
  unsigned short* wt_xbc  = (unsigned short*)alloc((size_t)128 * 1024 * 2);
  unsigned short* wt_dt   = (unsigned short*)alloc((size_t)1024 * 1024 * 2);
  unsigned short* wt_out  = (unsigned short*)alloc((size_t)1024 * 1024 * 2);
  unsigned short* U_bf    = (unsigned short*)alloc((size_t)1024 * 1024 * 2);  // (Wx_d@W_dt)^T
  unsigned short* x_bf    = (unsigned short*)alloc((size_t)M_ROWS * D_MODEL * 2);
  unsigned short* s_bf    = (unsigned short*)alloc((size_t)M_ROWS * D_MODEL * 2);  // silu(z)
  unsigned short* delta_bf= (unsigned short*)alloc((size_t)M_ROWS * D_MODEL * 2);
  unsigned short* g_bf    = (unsigned short*)alloc((size_t)M_ROWS * D_MODEL * 2);
  float* bssm_f           = (float*)alloc((size_t)M_ROWS * D_STATE * 4);
  float* cssm_f           = (float*)alloc((size_t)M_ROWS * D_STATE * 4);
  float* H_f              = (float*)alloc((size_t)NSEG * 4096 * 16 * 4);
  float* hinit_f          = (float*)alloc((size_t)NSEG * 4096 * 16 * 4);
  float* sdelta_f         = (float*)alloc((size_t)NSEG * 4096 * 4);
  float* res_f = (float*)x_bf;     // alias: x_bf+s_bf (16MB contiguous) consumed by scan1
                                   // before G4 writes res

  // 1. converts (x_in, W_x raw, smalls)
  convert_kernel<<<2656, 256, 0, stream>>>(x_in, x_in_b, W_x, wx_raw,
                                           b_dt, A_log, D_par, ln_g, ln_b,
                                           bdt_f, a2_f, dp_f, lng_f, lnb_f);
  // 2. transposes
  dim3 tb(32, 8);
  transpose_all_kernel<<<dim3(64, 32, 4), tb, 0, stream>>>(
      W_in, W_x, W_dt, W_out, wt_in, wt_xbc, wt_dt, wt_out, x_in);

  // 3. compose W_delta^T: U[m][n] = sum_k W_dt[k][m] * W_x[n][k']  (A=wt_dt, Bt=wx_raw)
  gemm_bf<0><<<dim3(16, 8), 256, 0, stream>>>(wt_dt, wx_raw, 1056,
      U_bf, nullptr, nullptr, nullptr, nullptr, nullptr, nullptr);

  // 4. G1: x_in @ W_in -> x, silu(z)
  gemm_bf<1><<<dim3(64, 16), 256, 0, stream>>>(x_in_b, wt_in, 1024,
      x_bf, s_bf, nullptr, nullptr, nullptr, nullptr, nullptr);

  // 5. G2': x @ [W_delta | W_bc] -> delta (softplus fused), B, C
  gemm_bf<2><<<dim3(64, 9), 256, 0, stream>>>(x_bf, U_bf, 1024,
      delta_bf, nullptr, wt_xbc, bssm_f, cssm_f, bdt_f, nullptr);

  // 6-8. scan
  scan_phase<0><<<1024, 256, 0, stream>>>(delta_bf, x_bf, nullptr, bssm_f, nullptr,
                                          a2_f, nullptr, nullptr, H_f, sdelta_f, nullptr);
  scan_phaseB<<<256, 256, 0, stream>>>(H_f, sdelta_f, a2_f, hinit_f);
  scan_phase<1><<<1024, 256, 0, stream>>>(delta_bf, x_bf, s_bf, bssm_f, cssm_f,
                                          a2_f, dp_f, hinit_f, nullptr, nullptr, g_bf);

  // 9. G4: g @ W_out + x_in -> res
  gemm_bf<4><<<dim3(64, 8), 256, 0, stream>>>(g_bf, wt_out, 1024,
      res_f, nullptr, nullptr, nullptr, nullptr, nullptr, x_in);

  // 10. LayerNorm
  ln_kernel<<<4096, 256, 0, stream>>>(res_f, lng_f, lnb_f, d_out, x_in);
}

// Round 9
// 256.265 us; speedup vs baseline: 1.6422x; 1.0393x over previous
//
#include <hip/hip_runtime.h>

#define D_MODEL 1024
#define D_STATE 16
#define M_ROWS  4096   // B*L
#define SEQ_L   1024
#define NSEG    64
#define LSEG    16     // SEQ_L / NSEG

typedef __bf16 bf16x8 __attribute__((ext_vector_type(8)));
typedef float  f32x4  __attribute__((ext_vector_type(4)));

__device__ __forceinline__ unsigned short f2bf(float f) {
  unsigned int u = __builtin_bit_cast(unsigned int, f);
  u += 0x7fffu + ((u >> 16) & 1u);           // RNE
  return (unsigned short)(u >> 16);
}
__device__ __forceinline__ float bf2f(unsigned short b) {
  unsigned int u = ((unsigned int)b) << 16;
  return __builtin_bit_cast(float, u);
}
__device__ __forceinline__ float load_elem(const void* p, size_t i, int isbf) {
  if (isbf) return bf2f(((const unsigned short*)p)[i]);
  return ((const float*)p)[i];
}

// Decentralized dtype detection: 64 samples of x_in's even u16s per wave.
// bf16 N(0,1): exponent in [100,135] for ~all lanes; fp32 low-mantissa u16s:
// ~uniform, ~9/64 in range. Threshold 32. Wave-uniform result.
__device__ __forceinline__ int is_bf16(const void* x_in) {
  unsigned int v = ((const unsigned short*)x_in)[2 * (threadIdx.x & 63)];
  unsigned int e = (v >> 7) & 0xFFu;
  unsigned long long m = __ballot(e >= 100u && e <= 135u);
  return __popcll(m) >= 32;
}

// async global->LDS, 16B per lane. LDS dest = (wave-uniform base) + lane*16.
__device__ __forceinline__ void gload16(const void* g, void* l) {
  typedef const __attribute__((address_space(1))) unsigned int GU;
  typedef __attribute__((address_space(3))) unsigned int LU;
  __builtin_amdgcn_global_load_lds((GU*)(unsigned long long)g,
                                   (LU*)(unsigned int)(unsigned long long)l,
                                   16, 0, 0);
}

// ---------------- prep: converts AND weight transposes in ONE launch ----------------
// bid <2048: x_in->bf16 | <2128: smalls | <2656: W_x->bf16 raw | >=2656: transposes
// transpose t = bid-2656: op0 W_in (64x32 tiles) [0,2048); op1 W_x cols 1024.. (4x32)
// [2048,2176); op2 W_dt [2176,3200); op3 W_out [3200,4224)
__global__ void prep_kernel(const void* __restrict__ x_in, unsigned short* __restrict__ x_b,
                            const void* __restrict__ W_in, const void* __restrict__ W_x,
                            const void* __restrict__ W_dt, const void* __restrict__ W_out,
                            unsigned short* __restrict__ wx_raw,
                            unsigned short* __restrict__ wt_in, unsigned short* __restrict__ wt_xbc,
                            unsigned short* __restrict__ wt_dt, unsigned short* __restrict__ wt_out,
                            const void* b_dt, const void* A_log, const void* Dp,
                            const void* ln_g, const void* ln_b,
                            float* o_bdt, float* o_a2, float* o_dp,
                            float* o_lng, float* o_lnb) {
  __shared__ float tile[32][33];
  const int isbf = is_bf16(x_in);
  const int bid = blockIdx.x;
  const int tid = threadIdx.x;
  if (bid < 2048 || (bid >= 2128 && bid < 2656)) {   // bulk bf16 conversion, 8 elems/thread
    const void* src; unsigned short* dst; int c;
    if (bid < 2048) { src = x_in; dst = x_b; c = bid * 256 + tid; }
    else { src = W_x; dst = wx_raw; c = (bid - 2128) * 256 + tid; }  // 135168 chunks
    if (isbf) {
      ((uint4*)dst)[c] = ((const uint4*)src)[c];
    } else {
      float4 a = ((const float4*)src)[2 * c];
      float4 b = ((const float4*)src)[2 * c + 1];
      uint4 p;
      p.x = (unsigned int)f2bf(a.x) | ((unsigned int)f2bf(a.y) << 16);
      p.y = (unsigned int)f2bf(a.z) | ((unsigned int)f2bf(a.w) << 16);
      p.z = (unsigned int)f2bf(b.x) | ((unsigned int)f2bf(b.y) << 16);
      p.w = (unsigned int)f2bf(b.z) | ((unsigned int)f2bf(b.w) << 16);
      ((uint4*)dst)[c] = p;
    }
  } else if (bid < 2128) {                   // smalls: 80 blocks, g in 0..20479
    int g = (bid - 2048) * 256 + tid;
    if (g < 1024)              o_bdt[g]          = load_elem(b_dt, g, isbf);
    else if (g < 17408) {
      float v = load_elem(A_log, g - 1024, isbf);
      o_a2[g - 1024] = -expf(v) * 1.4426950408889634f;
    }
    else if (g < 18432)        o_dp[g - 17408]   = load_elem(Dp, g - 17408, isbf);
    else if (g < 19456)        o_lng[g - 18432]  = load_elem(ln_g, g - 18432, isbf);
    else                       o_lnb[g - 19456]  = load_elem(ln_b, g - 19456, isbf);
  } else {                                   // transposes
    int t = bid - 2656;
    const void* src; unsigned short* dst; int ncols, col0, bxx, byy;
    if (t < 2048)      { src = W_in;  dst = wt_in;  ncols = 2048; col0 = 0;
                         bxx = t & 63; byy = t >> 6; }
    else if (t < 2176) { t -= 2048; src = W_x; dst = wt_xbc; ncols = 1056; col0 = 1024;
                         bxx = t & 3; byy = t >> 2; }
    else if (t < 3200) { t -= 2176; src = W_dt; dst = wt_dt; ncols = 1024; col0 = 0;
                         bxx = t & 31; byy = t >> 5; }
    else               { t -= 3200; src = W_out; dst = wt_out; ncols = 1024; col0 = 0;
                         bxx = t & 31; byy = t >> 5; }
    int tx = tid & 31, ty = tid >> 5;        // 32 x 8
    int n0 = col0 + bxx * 32, k0 = byy * 32;
    #pragma unroll
    for (int r = 0; r < 4; ++r) {
      int k = k0 + ty + r * 8;
      int n = n0 + tx;
      float v = (n < ncols) ? load_elem(src, (size_t)k * ncols + n, isbf) : 0.f;
      tile[ty + r * 8][tx] = v;
    }
    __syncthreads();
    #pragma unroll
    for (int r = 0; r < 4; ++r) {
      int n = n0 + ty + r * 8;
      int k = k0 + tx;
      dst[(size_t)(n - col0) * 1024 + k] = f2bf(tile[tx][ty + r * 8]);
    }
  }
}

// ---------------- bf16 MFMA GEMM, 64x128 tile, dist-2 pipelined LDS-DMA (R7-proven) ---
// MODE 1: G1 (bx<64): n<1024 -> x_bf; else silu -> s_bf. bx>=64: U-composition
//         rides along: C = wt_dt x wx_raw -> U_bf (bf16).   [grid 72x16]
// MODE 2: n<1024 -> softplus(v+aux[n]) -> delta_bf; n<1040 B f32; n<1056 C f32.
//         by==8 reads o2 (wt_xbc) rows n-1024.              [grid 64x9]
// MODE 4: o0 = f32 (v + x_in[m,n]), x_in raw (auxv), self-detected dtype
template<int MODE>
__global__ __launch_bounds__(256, 4) void gemm_bf(
    const unsigned short* __restrict__ A, const unsigned short* __restrict__ Bt, int ldb,
    void* __restrict__ o0, void* __restrict__ o1, void* __restrict__ o2,
    float* __restrict__ o3, float* __restrict__ o4,
    const float* __restrict__ aux, const void* __restrict__ auxv,
    const unsigned short* __restrict__ A_u, const unsigned short* __restrict__ B_u,
    int ldb_u, void* __restrict__ o_u) {
  __shared__ __align__(16) unsigned short a_lds[3][64 * 32];    // 12 KB
  __shared__ __align__(16) unsigned short b_lds[3][128 * 32];   // 24 KB
  const int isbf = (MODE == 4) ? is_bf16(auxv) : 0;
  const int tid = threadIdx.x;
  const int wave = tid >> 6, lane = tid & 63;
  const int wr = (wave >> 1) * 32, wc = (wave & 1) * 64;   // wave -> 32x64 sub-tile
  const int lrow = lane & 15, quad = lane >> 4;

  int m0, n0, ldbl = ldb;
  const unsigned short* Asrc = A;
  const unsigned short* Bsrc = Bt;
  bool isU = false;
  if (MODE == 1 && blockIdx.x >= 64) {       // U rides along G1
    isU = true;
    int u = (blockIdx.x - 64) * 16 + blockIdx.y;   // 0..127
    m0 = (u >> 3) * 64; n0 = (u & 7) * 128;
    Asrc = A_u; Bsrc = B_u; ldbl = ldb_u;
  } else {
    m0 = blockIdx.x * 64; n0 = blockIdx.y * 128;
    if (MODE == 2 && n0 >= 1024) { Bsrc = (const unsigned short*)o2; n0 -= 1024; }
  }
  const int nout = (MODE == 2 && Bsrc == (const unsigned short*)o2) ? n0 + 1024 : n0;

  // staging: lane l -> local row l>>2, 16B slot l&3 holding K-chunk
  // (l&3)^((l>>3)&3) (XOR swizzle; frag ds_read_b128 2-way aliased = free).
  const int sc = (lane & 3) ^ ((lane >> 3) & 3);
  const unsigned short* gA  = Asrc + (size_t)(m0 + wave * 16 + (lane >> 2)) * 1024 + sc * 8;
  const unsigned short* gB  = Bsrc + (size_t)(n0 + wave * 32 + (lane >> 2)) * ldbl + sc * 8;
  const unsigned short* gB2 = gB + (size_t)16 * ldbl;
  const int q2 = quad ^ ((lrow >> 1) & 3);

  f32x4 acc[2][4];
  #pragma unroll
  for (int i = 0; i < 2; ++i)
    #pragma unroll
    for (int j = 0; j < 4; ++j)
      #pragma unroll
      for (int r = 0; r < 4; ++r) acc[i][j][r] = 0.f;

  auto issue = [&](int k) {
    unsigned short* ab = a_lds[k % 3] + wave * 16 * 32;
    unsigned short* bb = b_lds[k % 3] + wave * 32 * 32;
    gload16(gA + k * 32, ab);
    gload16(gB + k * 32, bb);
    gload16(gB2 + k * 32, bb + 16 * 32);
  };
  auto compute = [&](int k) {
    const unsigned short* ard = a_lds[k % 3] + (wr + lrow) * 32 + q2 * 8;
    const unsigned short* brd = b_lds[k % 3] + (wc + lrow) * 32 + q2 * 8;
    bf16x8 af[2], bfr[4];
    #pragma unroll
    for (int i = 0; i < 2; ++i) af[i] = *(const bf16x8*)(ard + i * 16 * 32);
    #pragma unroll
    for (int j = 0; j < 4; ++j) bfr[j] = *(const bf16x8*)(brd + j * 16 * 32);
    #pragma unroll
    for (int i = 0; i < 2; ++i)
      #pragma unroll
      for (int j = 0; j < 4; ++j)
        acc[i][j] = __builtin_amdgcn_mfma_f32_16x16x32_bf16(af[i], bfr[j], acc[i][j], 0, 0, 0);
  };

  issue(0);
  issue(1);
  #pragma unroll
  for (int k = 0; k < 31; ++k) {
    asm volatile("s_waitcnt vmcnt(3)" ::: "memory");   // stage k landed, k+1 in flight
    __builtin_amdgcn_s_barrier();
    if (k + 2 < 32) issue(k + 2);
    compute(k);
  }
  asm volatile("s_waitcnt vmcnt(0)" ::: "memory");
  __builtin_amdgcn_s_barrier();
  compute(31);

  // C/D layout: row = quad*4 + r, col = lane&15.
  #pragma unroll
  for (int i = 0; i < 2; ++i) {
    #pragma unroll
    for (int jj = 0; jj < 4; ++jj) {
      #pragma unroll
      for (int r = 0; r < 4; ++r) {
        int m = m0 + wr + i * 16 + quad * 4 + r;
        int n = nout + wc + jj * 16 + lrow;
        float v = acc[i][jj][r];
        if (MODE == 1) {
          if (isU) {
            ((unsigned short*)o_u)[(size_t)m * 1024 + n] = f2bf(v);
          } else if (n < 1024) {
            ((unsigned short*)o0)[(size_t)m * 1024 + n] = f2bf(v);
          } else {
            float sig = 1.f / (1.f + expf(-v));
            ((unsigned short*)o1)[(size_t)m * 1024 + (n - 1024)] = f2bf(v * sig);
          }
        } else if (MODE == 2) {
          if (n < 1024) {
            float t = v + aux[n];
            float sp = (t > 20.f) ? t : log1pf(expf(t));
            ((unsigned short*)o0)[(size_t)m * 1024 + n] = f2bf(sp);
          }
          else if (n < 1040)  o3[(size_t)m * D_STATE + (n - 1024)] = v;
          else if (n < 1056)  o4[(size_t)m * D_STATE + (n - 1040)] = v;
          // n >= 1056: zero-padded columns, discard
        } else {  // MODE 4: residual from raw x_in
          ((float*)o0)[(size_t)m * 1024 + n] =
              v + load_elem(auxv, (size_t)m * 1024 + n, isbf);
        }
      }
    }
  }
}

// ---------------- chunked parallel scan (NSEG=64, LSEG=16) ----------------
template<int PHASE>
__global__ __launch_bounds__(256) void scan_phase(
    const unsigned short* __restrict__ dl_bf, const unsigned short* __restrict__ x_bf,
    const unsigned short* __restrict__ z_bf, const float* __restrict__ Bs,
    const float* __restrict__ Cs, const float* __restrict__ A2g,
    const float* __restrict__ Dpar, const float* __restrict__ hinit,
    float* __restrict__ Hout, float* __restrict__ sdout,
    unsigned short* __restrict__ g) {
  __shared__ float4 bsh[LSEG][4];
  __shared__ float4 csh[LSEG][4];
  const int tid = threadIdx.x;
  const int bid = blockIdx.x;                 // seg(64) x b(4) x dchunk(4) = 1024
  const int seg = bid >> 4;
  const int b = (bid >> 2) & 3;
  const int dc = bid & 3;
  const int d = dc * 256 + tid;
  const int t0 = seg * LSEG;
  const int bd = b * D_MODEL + d;

  if (tid < LSEG * 4) {                       // stage B (and C) segment rows
    int r = tid >> 2, q = tid & 3;
    size_t src = ((size_t)b * SEQ_L + t0 + r) * 4 + q;
    bsh[r][q] = ((const float4*)Bs)[src];
    if (PHASE == 1) csh[r][q] = ((const float4*)Cs)[src];
  }

  float A2r[16];
  {
    const float4* a4 = (const float4*)(A2g + (size_t)d * 16);
    #pragma unroll
    for (int q = 0; q < 4; ++q) {
      float4 v = a4[q];
      A2r[4*q] = v.x; A2r[4*q+1] = v.y; A2r[4*q+2] = v.z; A2r[4*q+3] = v.w;
    }
  }
  float h[16];
  if (PHASE == 1) {
    const float4* h4 = (const float4*)(hinit + (((size_t)seg * 4096) + bd) * 16);
    #pragma unroll
    for (int q = 0; q < 4; ++q) {
      float4 v = h4[q];
      h[4*q] = v.x; h[4*q+1] = v.y; h[4*q+2] = v.z; h[4*q+3] = v.w;
    }
  } else {
    #pragma unroll
    for (int n = 0; n < 16; ++n) h[n] = 0.f;
  }
  const float Dpd = (PHASE == 1) ? Dpar[d] : 0.f;
  float sd = 0.f;
  const size_t base = ((size_t)b * SEQ_L + t0) * D_MODEL + d;
  __syncthreads();

  unsigned short dreg[2][8], xreg[2][8], zreg[2][8];
  #pragma unroll
  for (int t = 0; t < 8; ++t) {
    size_t o = base + (size_t)t * D_MODEL;
    dreg[0][t] = dl_bf[o]; xreg[0][t] = x_bf[o];
    if (PHASE == 1) zreg[0][t] = z_bf[o];
  }
  #pragma unroll
  for (int c = 0; c < LSEG / 8; ++c) {
    const int cur = c & 1, nxt = cur ^ 1;
    if (c < LSEG / 8 - 1) {                   // prefetch next 8 steps
      #pragma unroll
      for (int t = 0; t < 8; ++t) {
        size_t o = base + (size_t)((c + 1) * 8 + t) * D_MODEL;
        dreg[nxt][t] = dl_bf[o]; xreg[nxt][t] = x_bf[o];
        if (PHASE == 1) zreg[nxt][t] = z_bf[o];
      }
    }
    #pragma unroll
    for (int t = 0; t < 8; ++t) {
      const int tt = c * 8 + t;
      float dl = bf2f(dreg[cur][t]);
      float xx = bf2f(xreg[cur][t]);
      float dx = dl * xx;
      sd += dl;
      float4 b0 = bsh[tt][0], b1 = bsh[tt][1], b2 = bsh[tt][2], b3 = bsh[tt][3];
      float bb[16] = {b0.x,b0.y,b0.z,b0.w, b1.x,b1.y,b1.z,b1.w,
                      b2.x,b2.y,b2.z,b2.w, b3.x,b3.y,b3.z,b3.w};
      if (PHASE == 0) {
        #pragma unroll
        for (int n = 0; n < 16; ++n) {
          float dA = exp2f(dl * A2r[n]);
          h[n] = fmaf(dA, h[n], dx * bb[n]);
        }
      } else {
        float4 c0 = csh[tt][0], c1 = csh[tt][1], c2 = csh[tt][2], c3 = csh[tt][3];
        float cc[16] = {c0.x,c0.y,c0.z,c0.w, c1.x,c1.y,c1.z,c1.w,
                        c2.x,c2.y,c2.z,c2.w, c3.x,c3.y,c3.z,c3.w};
        float y = 0.f;
        #pragma unroll
        for (int n = 0; n < 16; ++n) {
          float dA = exp2f(dl * A2r[n]);
          h[n] = fmaf(dA, h[n], dx * bb[n]);
          y = fmaf(h[n], cc[n], y);
        }
        float zz = bf2f(zreg[cur][t]);
        g[base + (size_t)tt * D_MODEL] = f2bf(fmaf(xx, Dpd, y) * zz);
      }
    }
  }
  if (PHASE == 0) {
    float4* ho = (float4*)(Hout + (((size_t)seg * 4096) + bd) * 16);
    #pragma unroll
    for (int q = 0; q < 4; ++q)
      ho[q] = make_float4(h[4*q], h[4*q+1], h[4*q+2], h[4*q+3]);
    sdout[(size_t)seg * 4096 + bd] = sd;
  }
}

// segment-level scan: h_init(s) = P(s-1)*h_init(s-1) + H(s-1), P = exp2(A2*sumdelta)
__global__ __launch_bounds__(256) void scan_phaseB(
    const float* __restrict__ H, const float* __restrict__ sdelta,
    const float* __restrict__ A2g, float* __restrict__ hinit) {
  int gidx = blockIdx.x * 256 + threadIdx.x;   // 65536 = bd(4096) x n(16)
  int bd = gidx >> 4, n = gidx & 15;
  float A2 = A2g[(size_t)(bd & (D_MODEL - 1)) * 16 + n];
  float hp = 0.f;
  #pragma unroll 8
  for (int s = 0; s < NSEG; ++s) {
    size_t idx = ((size_t)s * 4096 + bd) * 16 + n;
    hinit[idx] = hp;
    float P = exp2f(A2 * sdelta[(size_t)s * 4096 + bd]);
    hp = fmaf(P, hp, H[idx]);
  }
}

// ---------------- LayerNorm over D=1024 per row ----------------
__global__ __launch_bounds__(256) void ln_kernel(const float* __restrict__ res,
    const float* __restrict__ lng, const float* __restrict__ lnb,
    void* __restrict__ out, const void* __restrict__ x_in) {
  const int isbf = is_bf16(x_in);
  int row = blockIdx.x, tid = threadIdx.x;
  const float4* r4 = (const float4*)(res + (size_t)row * D_MODEL);
  float4 v = r4[tid];
  float s = v.x + v.y + v.z + v.w;
  float q = v.x * v.x + v.y * v.y + v.z * v.z + v.w * v.w;
  #pragma unroll
  for (int m = 1; m < 64; m <<= 1) { s += __shfl_xor(s, m); q += __shfl_xor(q, m); }
  __shared__ float ss[4], qs[4];
  int w = tid >> 6;
  if ((tid & 63) == 0) { ss[w] = s; qs[w] = q; }
  __syncthreads();
  s = ss[0] + ss[1] + ss[2] + ss[3];
  q = qs[0] + qs[1] + qs[2] + qs[3];
  float mu = s * (1.f / D_MODEL);
  float var = q * (1.f / D_MODEL) - mu * mu;
  float rstd = rsqrtf(var + 1e-5f);
  float4 gg = ((const float4*)lng)[tid];
  float4 bb = ((const float4*)lnb)[tid];
  float o0 = (v.x - mu) * rstd * gg.x + bb.x;
  float o1 = (v.y - mu) * rstd * gg.y + bb.y;
  float o2 = (v.z - mu) * rstd * gg.z + bb.z;
  float o3 = (v.w - mu) * rstd * gg.w + bb.w;
  if (isbf) {
    ushort4 pv;
    pv.x = f2bf(o0); pv.y = f2bf(o1); pv.z = f2bf(o2); pv.w = f2bf(o3);
    ((ushort4*)out)[(size_t)row * 256 + tid] = pv;
  } else {
    ((float4*)out)[(size_t)row * 256 + tid] = make_float4(o0, o1, o2, o3);
  }
}

extern "C" void kernel_launch(void* const* d_in, const int* in_sizes, int n_in,
                              void* d_out, int out_size, void* d_ws, size_t ws_size,
                              hipStream_t stream) {
  (void)in_sizes; (void)n_in; (void)out_size; (void)ws_size;
  const void* x_in  = d_in[0];
  const void* W_in  = d_in[1];
  const void* W_x   = d_in[2];
  const void* W_dt  = d_in[3];
  const void* b_dt  = d_in[4];
  const void* A_log = d_in[5];
  const void* D_par = d_in[6];
  const void* W_out = d_in[7];
  const void* ln_g  = d_in[8];
  const void* ln_b  = d_in[9];

  char* ws = (char*)d_ws;
  size_t off = 0;
  auto alloc = [&](size_t bytes) -> void* {
    void* p = ws + off;
    off += (bytes + 255) & ~(size_t)255;
    return p;
  };
  unsigned short* x_in_b  = (unsigned short*)alloc((size_t)M_ROWS * D_MODEL * 2);
  unsigned short* wx_raw  = (unsigned short*)alloc((size_t)1024 * 1056 * 2);  // W_x bf16 raw
  float* bdt_f            = (float*)alloc(1024 * 4);
  float* a2_f             = (float*)alloc(16384 * 4);
  float* dp_f             = (float*)alloc(1024 * 4);
  float* lng_f            = (float*)alloc(1024 * 4);
  float* lnb_f            = (float*)alloc(1024 * 4);
  unsigned short* wt_in   = (unsigned short*)alloc((size_t)2048 * 1024 * 2);
  unsigned short* wt_xbc  = (unsigned short*)alloc((size_t)128 * 1024 * 2);
  unsigned short* wt_dt   = (unsigned short*)alloc((size_t)1024 * 1024 * 2);
  unsigned short* wt_out  = (unsigned short*)alloc((size_t)1024 * 1024 * 2);
  unsigned short* U_bf    = (unsigned short*)alloc((size_t)1024 * 1024 * 2);  // (Wx_d@W_dt)^T
  unsigned short* x_bf    = (unsigned short*)alloc((size_t)M_ROWS * D_MODEL * 2);
  unsigned short* s_bf    = (unsigned short*)alloc((size_t)M_ROWS * D_MODEL * 2);  // silu(z)
  unsigned short* delta_bf= (unsigned short*)alloc((size_t)M_ROWS * D_MODEL * 2);
  unsigned short* g_bf    = (unsigned short*)alloc((size_t)M_ROWS * D_MODEL * 2);
  float* bssm_f           = (float*)alloc((size_t)M_ROWS * D_STATE * 4);
  float* cssm_f           = (float*)alloc((size_t)M_ROWS * D_STATE * 4);
  float* H_f              = (float*)alloc((size_t)NSEG * 4096 * 16 * 4);
  float* hinit_f          = (float*)alloc((size_t)NSEG * 4096 * 16 * 4);
  float* sdelta_f         = (float*)alloc((size_t)NSEG * 4096 * 4);
  float* res_f = (float*)x_bf;     // alias: x_bf+s_bf (16MB contiguous) consumed by scan1
                                   // before G4 writes res

  // 1. prep: all converts + all transposes (independent work, one launch)
  prep_kernel<<<6880, 256, 0, stream>>>(x_in, x_in_b, W_in, W_x, W_dt, W_out,
                                        wx_raw, wt_in, wt_xbc, wt_dt, wt_out,
                                        b_dt, A_log, D_par, ln_g, ln_b,
                                        bdt_f, a2_f, dp_f, lng_f, lnb_f);

  // 2. G1 (x_in @ W_in -> x, silu(z))  ∥  U-composition (wt_dt x wx_raw -> W_delta^T)
  gemm_bf<1><<<dim3(72, 16), 256, 0, stream>>>(x_in_b, wt_in, 1024,
      x_bf, s_bf, nullptr, nullptr, nullptr, nullptr, nullptr,
      wt_dt, wx_raw, 1056, U_bf);

  // 3. G2': x @ [W_delta | W_bc] -> delta (softplus fused), B, C
  gemm_bf<2><<<dim3(64, 9), 256, 0, stream>>>(x_bf, U_bf, 1024,
      delta_bf, nullptr, wt_xbc, bssm_f, cssm_f, bdt_f, nullptr,
      nullptr, nullptr, 0, nullptr);

  // 4-6. scan
  scan_phase<0><<<1024, 256, 0, stream>>>(delta_bf, x_bf, nullptr, bssm_f, nullptr,
                                          a2_f, nullptr, nullptr, H_f, sdelta_f, nullptr);
  scan_phaseB<<<256, 256, 0, stream>>>(H_f, sdelta_f, a2_f, hinit_f);
  scan_phase<1><<<1024, 256, 0, stream>>>(delta_bf, x_bf, s_bf, bssm_f, cssm_f,
                                          a2_f, dp_f, hinit_f, nullptr, nullptr, g_bf);

  // 7. G4: g @ W_out + x_in -> res
  gemm_bf<4><<<dim3(64, 8), 256, 0, stream>>>(g_bf, wt_out, 1024,
      res_f, nullptr, nullptr, nullptr, nullptr, nullptr, x_in,
      nullptr, nullptr, 0, nullptr);

  // 8. LayerNorm
  ln_kernel<<<4096, 256, 0, stream>>>(res_f, lng_f, lnb_f, d_out, x_in);
}